// Round 5
// baseline (583.223 us; speedup 1.0000x reference)
//
#include <hip/hip_runtime.h>
#include <math.h>

#define HD 64
#define WPB 2

typedef unsigned short u16;
typedef unsigned int u32;
typedef __attribute__((ext_vector_type(8))) short short8;
typedef __attribute__((ext_vector_type(4))) float f32x4;

__device__ __forceinline__ u16 f2bf(float f) {
  return (u16)((__float_as_uint(f) + 0x8000u) >> 16);  // round-half-up
}
__device__ __forceinline__ float bf2f(u16 x) {
  return __uint_as_float(((u32)x) << 16);
}
__device__ __forceinline__ int uswz(int row, int col) {
  return ((row << 6) | col) ^ ((row & 7) << 3);
}
__device__ __forceinline__ float rlane(float v, int l) {
  return __uint_as_float(__builtin_amdgcn_readlane(__float_as_uint(v), l));
}

// ---- phase descriptors -----------------------------------------------------
// widx[0:4] | asel[5:6] | dsel[7:8] | mt2[9] | epi[10:12] | bsel[13:16] |
// post[17:19] | nozacc[20] | d512[21]
// asel/dsel: 0=H,1=K,2=T,3=U.  epi: 0 skip,1 store,2 relu,3 MULT,4 RESID,
// 5 VRED,6 CRED,7 HOUT.  post: 0 none,1 EINSUM,2 EDGEASM,3 NAGG,4 COORD.
#define PH(w, a, ds, m2, e, b, p, nz, d5)                                   \
  ((u32)(w) | ((u32)(a) << 5) | ((u32)(ds) << 7) | ((u32)(m2) << 9) |       \
   ((u32)(e) << 10) | ((u32)(b) << 13) | ((u32)(p) << 17) |                 \
   ((u32)(nz) << 20) | ((u32)(d5) << 21))

static __device__ const u32 PHT[16] = {
    PH(1, 1, 2, 1, 2, 2, 0, 0, 0),   // P0  K@W1  relu->T   b=br_b1+64
    PH(4, 2, 3, 1, 2, 5, 0, 0, 0),   // P1  T@W4  relu->U   b=br_b2+64  (k0)
    PH(2, 1, 2, 1, 2, 3, 0, 0, 0),   // P2  K@W2  relu->T   b=br_b1+128
    PH(5, 2, 2, 1, 2, 6, 1, 0, 0),   // P3  T@W5  relu->T   b=br_b2+128 (k1) +EINSUM
    PH(0, 1, 2, 1, 2, 1, 0, 0, 0),   // P4  K@W0  relu->T   b=br_b1     (sm L1)
    PH(3, 2, 2, 1, 3, 4, 0, 0, 0),   // P5  T@W3  MULT->T   b=br_b2     (z)
    PH(6, 2, 1, 1, 4, 7, 0, 0, 0),   // P6  T@W6  RESID->K  b=out_b
    PH(9, 1, 2, 1, 1, 0, 0, 0, 0),   // P7  K@W9  store->T  (accC)
    PH(7, 0, 3, 0, 1, 0, 0, 0, 0),   // P8  H@W7  store->U  (accA)
    PH(8, 0, 3, 0, 1, 0, 0, 0, 1),   // P9  H@W8  store->U+512 (accB)
    PH(12, 0, 0, 0, 5, 0, 2, 0, 0),  // P10 H@W12 VRED      +EDGEASM
    PH(10, 2, 3, 1, 2, 8, 3, 0, 0),  // P11 T@W10 relu->U   b=e_b2      +NAGG
    PH(11, 3, 0, 1, 6, 0, 4, 0, 0),  // P12 U@W11 CRED      +COORD
    PH(13, 0, 0, 0, 0, 0, 0, 0, 0),  // P13 H@W13 skip (acc init)
    PH(14, 1, 2, 0, 2, 9, 0, 1, 0),  // P14 K@W14 relu->T   b=n_b1 (nozacc)
    PH(15, 2, 0, 0, 7, 10, 0, 0, 0), // P15 T@W15 HOUT      (n_b2)
};

// ---- pre-pass: pack weights to bf16 transposed [n][k] ----
__global__ __launch_bounds__(256) void prepack(
    const float* __restrict__ br_w1, const float* __restrict__ br_w2,
    const float* __restrict__ out_w, const float* __restrict__ e_w1,
    const float* __restrict__ e_w2, const float* __restrict__ c_w1,
    const float* __restrict__ v_w1, const float* __restrict__ n_w1,
    const float* __restrict__ n_w2, const float* __restrict__ ic_wef,
    u16* __restrict__ W) {
  const int m = blockIdx.x;
  if (m == 16) {  // ic_wef^T, K padded 12->32 with zeros
    for (int e = threadIdx.x; e < 2048; e += blockDim.x) {
      const int n = e >> 5, k = e & 31;
      W[16 * 4096 + e] = (k < 12) ? f2bf(ic_wef[k * 64 + n]) : (u16)0;
    }
    return;
  }
  const float* src;
  switch (m) {
    case 0: src = br_w1; break;
    case 1: src = br_w1 + 4096; break;
    case 2: src = br_w1 + 8192; break;
    case 3: src = br_w2; break;
    case 4: src = br_w2 + 4096; break;
    case 5: src = br_w2 + 8192; break;
    case 6: src = out_w; break;
    case 7: src = e_w1; break;             // h[row]
    case 8: src = e_w1 + 64 * 64; break;   // h[col]
    case 9: src = e_w1 + 129 * 64; break;  // kemb
    case 10: src = e_w2; break;
    case 11: src = c_w1; break;
    case 12: src = v_w1; break;
    case 13: src = n_w1; break;            // h half
    case 14: src = n_w1 + 64 * 64; break;  // nagg half
    default: src = n_w2; break;
  }
  u16* dst = W + m * 4096;
  for (int e = threadIdx.x; e < 4096; e += blockDim.x) {
    const int n = e >> 6, k = e & 63;
    dst[e] = f2bf(src[k * 64 + n]);
  }
}

__global__ __launch_bounds__(64 * WPB, 4) void egcl_mfma(
    const float* __restrict__ gh, const float* __restrict__ gcoord,
    const float* __restrict__ gvel, const u16* __restrict__ Wg,
    const float* __restrict__ e_w1, const float* __restrict__ e_b1,
    const float* __restrict__ e_b2,
    const float* __restrict__ n_b1, const float* __restrict__ n_b2,
    const float* __restrict__ c_b1, const float* __restrict__ c_w2,
    const float* __restrict__ v_b1, const float* __restrict__ v_w2,
    const float* __restrict__ v_b2,
    const float* __restrict__ ic_pat,
    const float* __restrict__ br_b1, const float* __restrict__ br_b2,
    const float* __restrict__ out_b,
    float* __restrict__ hout, float* __restrict__ cout, int B) {
  // 5120 u16 per wave: H[5][64]@0, K@320, T@1920, U@3520 (each [25][64] swz)
  __shared__ __align__(16) u16 arena[WPB][5120];

  const int t = threadIdx.x & 63;
  const int wv = threadIdx.x >> 6;
  const int g = blockIdx.x * WPB + wv;
  if (g >= B) return;  // waves independent; no block barriers anywhere

  u16* AR = arena[wv];
  u16* K_ = AR + 320;
  u16* T_ = AR + 1920;
  u16* U_ = AR + 3520;
  u16* EFa = T_;  // EF lives in T before T's first matmul use: [25][32] plain
  const int c15 = t & 15, q = t >> 4, q8 = q << 3;

  // ---------------- prologue: inputs ----------------
  float scvreg = 0.0f;
  if (t < 15) scvreg = gcoord[g * 15 + t];
  else if (t >= 16 && t < 31) scvreg = gvel[g * 15 + (t - 16)];

#pragma unroll
  for (int i = 0; i < 5; ++i) AR[uswz(i, t)] = f2bf(gh[(g * 5 + i) * HD + t]);

  // zero EF cols 12..31 (rows 0..24): 250 u32 slots
#pragma unroll
  for (int z = 0; z < 4; ++z) {
    const int e = t + z * 64;
    if (e < 250) {
      const int row = e / 10, cc = 12 + (e % 10) * 2;
      *reinterpret_cast<u32*>(EFa + row * 32 + cc) = 0u;
    }
  }

  float sqcc = 0.0f;  // squared coord-dist for this lane's tuple (radial)
  if (t < 25) {
    const int ti = t / 5, tj = t % 5;
    const float cix = __shfl(scvreg, ti * 3 + 0, 64), ciy = __shfl(scvreg, ti * 3 + 1, 64), ciz = __shfl(scvreg, ti * 3 + 2, 64);
    const float cjx = __shfl(scvreg, tj * 3 + 0, 64), cjy = __shfl(scvreg, tj * 3 + 1, 64), cjz = __shfl(scvreg, tj * 3 + 2, 64);
    const float vix = __shfl(scvreg, 16 + ti * 3 + 0, 64), viy = __shfl(scvreg, 16 + ti * 3 + 1, 64), viz = __shfl(scvreg, 16 + ti * 3 + 2, 64);
    const float vjx = __shfl(scvreg, 16 + tj * 3 + 0, 64), vjy = __shfl(scvreg, 16 + tj * 3 + 1, 64), vjz = __shfl(scvreg, 16 + tj * 3 + 2, 64);
    {
      const float dx = cix - cjx, dy = ciy - cjy, dz = ciz - cjz;
      sqcc = dx * dx + dy * dy + dz * dz;
    }
    auto sd = [](float sq) { return (sq > 0.0f) ? sqrtf(sq) : 0.0f; };
    float sq2;
    const float dcc = sd(sqcc);
    {
      const float dx = vix - vjx, dy = viy - vjy, dz = viz - vjz;
      sq2 = dx * dx + dy * dy + dz * dz;
    }
    const float dvv = sd(sq2);
    {
      const float dx = cix - vjx, dy = ciy - vjy, dz = ciz - vjz;
      sq2 = dx * dx + dy * dy + dz * dz;
    }
    const float dcv = sd(sq2);
    {
      const float dx = cjx - vix, dy = cjy - viy, dz = cjz - viz;
      sq2 = dx * dx + dy * dy + dz * dz;
    }
    const float dvc = sd(sq2);
    auto rbf3 = [&](float d, int base) {
      const float cut = (d <= 10.0f) ? (0.5f * (cosf(d * 0.31415926535897931f) + 1.0f)) : 0.0f;
      const float e = expf(-0.5f * d);
      const float u0 = e - 4.5399929762484854e-05f;
      const float u1 = e - 0.50002270f;
      const float u2 = e - 1.0f;
      const float BETA = 2.2502043f;
      EFa[t * 32 + base + 0] = f2bf((cut * expf(-BETA * u0 * u0) - 0.05f) * (1.0f / 0.15f));
      EFa[t * 32 + base + 1] = f2bf((cut * expf(-BETA * u1 * u1) - 0.05f) * (1.0f / 0.15f));
      EFa[t * 32 + base + 2] = f2bf((cut * expf(-BETA * u2 * u2) - 0.05f) * (1.0f / 0.15f));
    };
    rbf3(dcc, 0);
    rbf3(dvv, 3);
    rbf3(dcv, 6);
    rbf3(dvc, 9);
  }

  f32x4 acc[2][4];
  float svv[4];
  float svc[2][4];

  // ---------------- kemb = (ef @ ic_wef) * ic_pat[pattern] -> K ------------
  {
#pragma unroll
    for (int mt = 0; mt < 2; ++mt)
#pragma unroll
      for (int nt = 0; nt < 4; ++nt) acc[mt][nt] = (f32x4){0.f, 0.f, 0.f, 0.f};
    const u16* WTp = Wg + 16 * 4096;
    short8 bfr[4];
#pragma unroll
    for (int nt = 0; nt < 4; ++nt)
      bfr[nt] = *reinterpret_cast<const short8*>(WTp + (nt * 16 + c15) * 32 + q8);
#pragma unroll
    for (int mt = 0; mt < 2; ++mt) {
      int row = mt * 16 + c15;
      row = row > 24 ? 24 : row;
      const short8 a = *reinterpret_cast<const short8*>(EFa + row * 32 + q8);
#pragma unroll
      for (int nt = 0; nt < 4; ++nt)
        acc[mt][nt] = __builtin_amdgcn_mfma_f32_16x16x32_bf16(a, bfr[nt], acc[mt][nt], 0, 0, 0);
    }
#pragma unroll
    for (int nt = 0; nt < 4; ++nt) {
      const int col = nt * 16 + c15;
      const float p1 = ic_pat[64 + col], p2 = ic_pat[128 + col];
#pragma unroll
      for (int mt = 0; mt < 2; ++mt)
#pragma unroll
        for (int i = 0; i < 4; ++i) {
          const int row = mt * 16 + q * 4 + i;
          if (row < 25) {
            const bool diag = (row % 6) == 0;  // tuples 0,6,12,18,24
            K_[uswz(row, col)] = f2bf(acc[mt][nt][i] * (diag ? p2 : p1));
          }
        }
    }
  }

  // ---------------- descriptor-driven phase loop ----------------
#pragma unroll 1
  for (int ph = 0; ph < 16; ++ph) {
    const u32 d = PHT[ph];
    const int widx = d & 31;
    const int asel = (d >> 5) & 3;
    const int dsel = (d >> 7) & 3;
    const int mtn = ((d >> 9) & 1) + 1;
    const int epi = (d >> 10) & 7;
    const int bsel = (d >> 13) & 15;
    const int post = (d >> 17) & 7;
    const int rmax = (mtn == 2) ? 24 : 4;
    const int rowlim = (mtn == 2) ? 25 : 5;
    const u16* A_ = AR + (asel == 0 ? 0 : asel == 1 ? 320 : asel == 2 ? 1920 : 3520);
    u16* D_ = AR + (dsel == 0 ? 0 : dsel == 1 ? 320 : dsel == 2 ? 1920 : 3520) +
              (((d >> 21) & 1) << 9);

    // bias (vector-per-col); loaded early so vm-latency hides under MFMAs
    const float* bp = nullptr;
    switch (bsel) {
      case 1: bp = br_b1; break;
      case 2: bp = br_b1 + 64; break;
      case 3: bp = br_b1 + 128; break;
      case 4: bp = br_b2; break;
      case 5: bp = br_b2 + 64; break;
      case 6: bp = br_b2 + 128; break;
      case 7: bp = out_b; break;
      case 8: bp = e_b2; break;
      case 9: bp = n_b1; break;
      case 10: bp = n_b2; break;
      default: break;
    }
    float bb[4] = {0.f, 0.f, 0.f, 0.f};
    if (bp) {
#pragma unroll
      for (int nt = 0; nt < 4; ++nt) bb[nt] = bp[nt * 16 + c15];
    }

    // B fragments
    const u16* WTp = Wg + (widx << 12);
    short8 bfr[4][2];
#pragma unroll
    for (int nt = 0; nt < 4; ++nt)
#pragma unroll
      for (int s = 0; s < 2; ++s)
        bfr[nt][s] = *reinterpret_cast<const short8*>(WTp + (nt * 16 + c15) * 64 + s * 32 + q8);

    if (!((d >> 20) & 1)) {
#pragma unroll
      for (int mt = 0; mt < 2; ++mt)
#pragma unroll
        for (int nt = 0; nt < 4; ++nt) acc[mt][nt] = (f32x4){0.f, 0.f, 0.f, 0.f};
    }

#pragma unroll
    for (int mt = 0; mt < 2; ++mt) {
      if (mt < mtn) {
        int row = mt * 16 + c15;
        row = row > rmax ? rmax : row;
        const int idx = ((row << 6) | q8) ^ ((row & 7) << 3);
        const short8 a0 = *reinterpret_cast<const short8*>(A_ + idx);
        const short8 a1 = *reinterpret_cast<const short8*>(A_ + (idx ^ 32));
#pragma unroll
        for (int nt = 0; nt < 4; ++nt)
          acc[mt][nt] = __builtin_amdgcn_mfma_f32_16x16x32_bf16(a0, bfr[nt][0], acc[mt][nt], 0, 0, 0);
#pragma unroll
        for (int nt = 0; nt < 4; ++nt)
          acc[mt][nt] = __builtin_amdgcn_mfma_f32_16x16x32_bf16(a1, bfr[nt][1], acc[mt][nt], 0, 0, 0);
      }
    }

    // ---- epilogue ----
    switch (epi) {
      case 1:
      case 2: {  // store / relu+bias
        const bool dorelu = (epi == 2);
#pragma unroll
        for (int nt = 0; nt < 4; ++nt) {
          const int col = nt * 16 + c15;
#pragma unroll
          for (int mt = 0; mt < 2; ++mt)
            if (mt < mtn)
#pragma unroll
              for (int i = 0; i < 4; ++i) {
                const int row = mt * 16 + q * 4 + i;
                if (row < rowlim) {
                  float v = acc[mt][nt][i] + bb[nt];
                  if (dorelu) v = fmaxf(v, 0.0f);
                  D_[uswz(row, col)] = f2bf(v);
                }
              }
        }
      } break;
      case 3: {  // MULT: D = relu(acc+b) * U (elementwise)
#pragma unroll
        for (int nt = 0; nt < 4; ++nt) {
          const int col = nt * 16 + c15;
#pragma unroll
          for (int mt = 0; mt < 2; ++mt)
#pragma unroll
            for (int i = 0; i < 4; ++i) {
              const int row = mt * 16 + q * 4 + i;
              if (row < 25) {
                const int ix = uswz(row, col);
                const float sv = fmaxf(acc[mt][nt][i] + bb[nt], 0.0f);
                D_[ix] = f2bf(sv * bf2f(U_[ix]));
              }
            }
        }
      } break;
      case 4: {  // RESID: D += relu(acc+b)
#pragma unroll
        for (int nt = 0; nt < 4; ++nt) {
          const int col = nt * 16 + c15;
#pragma unroll
          for (int mt = 0; mt < 2; ++mt)
#pragma unroll
            for (int i = 0; i < 4; ++i) {
              const int row = mt * 16 + q * 4 + i;
              if (row < 25) {
                const int ix = uswz(row, col);
                D_[ix] = f2bf(fmaxf(acc[mt][nt][i] + bb[nt], 0.0f) + bf2f(D_[ix]));
              }
            }
        }
      } break;
      case 5: {  // VRED: v-model reduction -> svv
#pragma unroll
        for (int i = 0; i < 4; ++i) {
          float s = 0.0f;
#pragma unroll
          for (int nt = 0; nt < 4; ++nt) {
            const int col = nt * 16 + c15;
            s += fmaxf(acc[0][nt][i] + v_b1[col], 0.0f) * v_w2[col];
          }
          s += __shfl_xor(s, 1, 64);
          s += __shfl_xor(s, 2, 64);
          s += __shfl_xor(s, 4, 64);
          s += __shfl_xor(s, 8, 64);
          svv[i] = s;
        }
      } break;
      case 6: {  // CRED: c-model reduction -> svc
#pragma unroll
        for (int mt = 0; mt < 2; ++mt)
#pragma unroll
          for (int i = 0; i < 4; ++i) {
            float s = 0.0f;
#pragma unroll
            for (int nt = 0; nt < 4; ++nt) {
              const int col = nt * 16 + c15;
              s += fmaxf(acc[mt][nt][i] + c_b1[col], 0.0f) * c_w2[col];
            }
            s += __shfl_xor(s, 1, 64);
            s += __shfl_xor(s, 2, 64);
            s += __shfl_xor(s, 4, 64);
            s += __shfl_xor(s, 8, 64);
            svc[mt][i] = s;
          }
      } break;
      case 7: {  // HOUT: hout = gh + acc + n_b2
#pragma unroll
        for (int nt = 0; nt < 4; ++nt) {
          const int col = nt * 16 + c15;
#pragma unroll
          for (int i = 0; i < 4; ++i) {
            const int row = q * 4 + i;
            if (row < 5) {
              const size_t ix = (size_t)(g * 5 + row) * HD + col;
              hout[ix] = gh[ix] + acc[0][nt][i] + bb[nt];
            }
          }
        }
      } break;
      default: break;  // skip (P13)
    }

    // ---- post ops (one copy each) ----
    switch (post) {
      case 1: {  // EINSUM: mult = k0(U) @ k1(T) per channel -> U
        float mu[25];
#pragma unroll
        for (int p = 0; p < 25; ++p) mu[p] = 0.0f;
#pragma unroll
        for (int j = 0; j < 5; ++j) {
          float k1r[5], k0c[5];
#pragma unroll
          for (int k = 0; k < 5; ++k) k1r[k] = bf2f(T_[uswz(j * 5 + k, t)]);
#pragma unroll
          for (int i = 0; i < 5; ++i) k0c[i] = bf2f(U_[uswz(i * 5 + j, t)]);
#pragma unroll
          for (int i = 0; i < 5; ++i)
#pragma unroll
            for (int k = 0; k < 5; ++k) mu[i * 5 + k] = fmaf(k0c[i], k1r[k], mu[i * 5 + k]);
        }
#pragma unroll
        for (int p = 0; p < 25; ++p) U_[uswz(p, t)] = f2bf(mu[p]);
      } break;
      case 2: {  // EDGEASM: edge pre-act -> T rows 0-19
        float aAc[5], aBc[5];
#pragma unroll
        for (int i = 0; i < 5; ++i) {
          aAc[i] = bf2f(U_[uswz(i, t)]);
          aBc[i] = bf2f(U_[uswz(8 + i, t)]);
        }
        const float eb1v = e_b1[t];
        const float wradv = e_w1[128 * HD + t];
        float ec[20];
#pragma unroll
        for (int p = 0; p < 20; ++p) {
          const int i = p >> 2, jj = p & 3;
          const int j = jj + (jj >= i ? 1 : 0);
          const float radial = rlane(sqcc, i * 5 + j);
          const float cc = bf2f(T_[uswz(i * 5 + j, t)]);
          ec[p] = fmaxf(aAc[i] + aBc[j] + radial * wradv + cc + eb1v, 0.0f);
        }
#pragma unroll
        for (int p = 0; p < 20; ++p) T_[uswz(p, t)] = f2bf(ec[p]);
      } break;
      case 3: {  // NAGG: segment-sum edge_feat(U) -> K rows 0-4
#pragma unroll
        for (int i = 0; i < 5; ++i) {
          float na = 0.0f;
#pragma unroll
          for (int jj = 0; jj < 4; ++jj) na += bf2f(U_[uswz(4 * i + jj, t)]);
          K_[uswz(i, t)] = f2bf(na);
        }
      } break;
      case 4: {  // COORD: coord update + cout write
        const float vb2 = v_b2[0];
        float coutreg = 0.0f;
#pragma unroll
        for (int i = 0; i < 5; ++i) {
          const float vmi = rlane(svv[i & 3], (i >> 2) << 4) + vb2;
#pragma unroll
          for (int dd = 0; dd < 3; ++dd) {
            const float ci = rlane(scvreg, i * 3 + dd);
            float s = 0.0f;
#pragma unroll
            for (int jj = 0; jj < 4; ++jj) {
              const int j = jj + (jj >= i ? 1 : 0);
              const int p = i * 4 + jj;
              const float cmp = rlane(svc[p >> 4][p & 3], ((p & 15) >> 2) << 4);
              float tr = (ci - rlane(scvreg, j * 3 + dd)) * cmp;
              tr = fminf(fmaxf(tr, -100.0f), 100.0f);
              s += tr;
            }
            const float val = ci + 0.25f * s + rlane(scvreg, 16 + i * 3 + dd) * vmi;
            if (t == i * 3 + dd) coutreg = val;
          }
        }
        if (t < 15) cout[g * 15 + t] = coutreg;
      } break;
      default: break;
    }
  }
}

extern "C" void kernel_launch(void* const* d_in, const int* in_sizes, int n_in,
                              void* d_out, int out_size, void* d_ws, size_t ws_size,
                              hipStream_t stream) {
  if (n_in < 27) return;
  const float* gh    = (const float*)d_in[0];
  const float* coord = (const float*)d_in[1];
  const float* vel   = (const float*)d_in[2];
  const float* e_w1 = (const float*)d_in[4];
  const float* e_b1 = (const float*)d_in[5];
  const float* e_w2 = (const float*)d_in[6];
  const float* e_b2 = (const float*)d_in[7];
  const float* n_w1 = (const float*)d_in[8];
  const float* n_b1 = (const float*)d_in[9];
  const float* n_w2 = (const float*)d_in[10];
  const float* n_b2 = (const float*)d_in[11];
  const float* c_w1 = (const float*)d_in[12];
  const float* c_b1 = (const float*)d_in[13];
  const float* c_w2 = (const float*)d_in[14];
  const float* v_w1 = (const float*)d_in[15];
  const float* v_b1 = (const float*)d_in[16];
  const float* v_w2 = (const float*)d_in[17];
  const float* v_b2 = (const float*)d_in[18];
  const float* ic_wef = (const float*)d_in[19];
  const float* ic_pat = (const float*)d_in[20];
  const float* br_w1 = (const float*)d_in[21];
  const float* br_b1 = (const float*)d_in[22];
  const float* br_w2 = (const float*)d_in[23];
  const float* br_b2 = (const float*)d_in[24];
  const float* out_w = (const float*)d_in[25];
  const float* out_b = (const float*)d_in[26];

  const int N = in_sizes[0] / HD;  // 100000
  const int B = N / 5;             // 20000 graphs
  float* hout = (float*)d_out;
  float* cout = (float*)d_out + (size_t)N * HD;
  u16* W = (u16*)d_ws;  // 16*4096 + 2048 u16 = 135168 B

  prepack<<<17, 256, 0, stream>>>(br_w1, br_w2, out_w, e_w1, e_w2, c_w1, v_w1,
                                  n_w1, n_w2, ic_wef, W);

  const int blocks = (B + WPB - 1) / WPB;
  egcl_mfma<<<blocks, 64 * WPB, 0, stream>>>(
      gh, coord, vel, W, e_w1, e_b1, e_b2, n_b1, n_b2, c_b1, c_w2, v_b1, v_w2,
      v_b2, ic_pat, br_b1, br_b2, out_b, hout, cout, B);
}

// Round 6
// 467.080 us; speedup vs baseline: 1.2487x; 1.2487x over previous
//
#include <hip/hip_runtime.h>
#include <math.h>

#define HD 64
#define WPB 2

typedef unsigned short u16;
typedef unsigned int u32;
typedef __attribute__((ext_vector_type(8))) short short8;
typedef __attribute__((ext_vector_type(4))) float f32x4;

__device__ __forceinline__ u16 f2bf(float f) {
  return (u16)((__float_as_uint(f) + 0x8000u) >> 16);  // round-half-up
}
__device__ __forceinline__ float bf2f(u16 x) {
  return __uint_as_float(((u32)x) << 16);
}
__device__ __forceinline__ int uswz(int row, int col) {
  return ((row << 6) | col) ^ ((row & 7) << 3);
}
__device__ __forceinline__ float rlane(float v, int l) {
  return __uint_as_float(__builtin_amdgcn_readlane(__float_as_uint(v), l));
}

// ---- phase descriptors -----------------------------------------------------
// widx[0:4] | asel[5:6] | dsel[7:8] | mt2[9] | epi[10:12] | bsel[13:16] |
// post[17:19] | nozacc[20] | d512[21]
// asel/dsel: 0=H,1=K,2=T,3=U.  epi: 0 skip,1 store,2 relu,3 MULT,4 RESID,
// 5 VRED,6 CRED,7 HOUT.  post: 0 none,1 EINSUM,2 EDGEASM,3 NAGG,4 COORD.
#define PH(w, a, ds, m2, e, b, p, nz, d5)                                   \
  ((u32)(w) | ((u32)(a) << 5) | ((u32)(ds) << 7) | ((u32)(m2) << 9) |       \
   ((u32)(e) << 10) | ((u32)(b) << 13) | ((u32)(p) << 17) |                 \
   ((u32)(nz) << 20) | ((u32)(d5) << 21))

static __device__ const u32 PHT[16] = {
    PH(1, 1, 2, 1, 2, 2, 0, 0, 0),   // P0  K@W1  relu->T   b=br_b1+64
    PH(4, 2, 3, 1, 2, 5, 0, 0, 0),   // P1  T@W4  relu->U   b=br_b2+64  (k0)
    PH(2, 1, 2, 1, 2, 3, 0, 0, 0),   // P2  K@W2  relu->T   b=br_b1+128
    PH(5, 2, 2, 1, 2, 6, 1, 0, 0),   // P3  T@W5  relu->T   b=br_b2+128 (k1) +EINSUM
    PH(0, 1, 2, 1, 2, 1, 0, 0, 0),   // P4  K@W0  relu->T   b=br_b1     (sm L1)
    PH(3, 2, 2, 1, 3, 4, 0, 0, 0),   // P5  T@W3  MULT->T   b=br_b2     (z)
    PH(6, 2, 1, 1, 4, 7, 0, 0, 0),   // P6  T@W6  RESID->K  b=out_b
    PH(9, 1, 2, 1, 1, 0, 0, 0, 0),   // P7  K@W9  store->T  (accC)
    PH(7, 0, 3, 0, 1, 0, 0, 0, 0),   // P8  H@W7  store->U  (accA)
    PH(8, 0, 3, 0, 1, 0, 0, 0, 1),   // P9  H@W8  store->U+512 (accB)
    PH(12, 0, 0, 0, 5, 0, 2, 0, 0),  // P10 H@W12 VRED      +EDGEASM
    PH(10, 2, 3, 1, 2, 8, 3, 0, 0),  // P11 T@W10 relu->U   b=e_b2      +NAGG
    PH(11, 3, 0, 1, 6, 0, 4, 0, 0),  // P12 U@W11 CRED      +COORD
    PH(13, 0, 0, 0, 0, 0, 0, 0, 0),  // P13 H@W13 skip (acc init)
    PH(14, 1, 2, 0, 2, 9, 0, 1, 0),  // P14 K@W14 relu->T   b=n_b1 (nozacc)
    PH(15, 2, 0, 0, 7, 10, 0, 0, 0), // P15 T@W15 HOUT      (n_b2)
};

// ---- pre-pass: pack weights to bf16 transposed [n][k] ----
__global__ __launch_bounds__(256) void prepack(
    const float* __restrict__ br_w1, const float* __restrict__ br_w2,
    const float* __restrict__ out_w, const float* __restrict__ e_w1,
    const float* __restrict__ e_w2, const float* __restrict__ c_w1,
    const float* __restrict__ v_w1, const float* __restrict__ n_w1,
    const float* __restrict__ n_w2, const float* __restrict__ ic_wef,
    u16* __restrict__ W) {
  const int m = blockIdx.x;
  if (m == 16) {  // ic_wef^T, K padded 12->32 with zeros
    for (int e = threadIdx.x; e < 2048; e += blockDim.x) {
      const int n = e >> 5, k = e & 31;
      W[16 * 4096 + e] = (k < 12) ? f2bf(ic_wef[k * 64 + n]) : (u16)0;
    }
    return;
  }
  const float* src;
  switch (m) {
    case 0: src = br_w1; break;
    case 1: src = br_w1 + 4096; break;
    case 2: src = br_w1 + 8192; break;
    case 3: src = br_w2; break;
    case 4: src = br_w2 + 4096; break;
    case 5: src = br_w2 + 8192; break;
    case 6: src = out_w; break;
    case 7: src = e_w1; break;             // h[row]
    case 8: src = e_w1 + 64 * 64; break;   // h[col]
    case 9: src = e_w1 + 129 * 64; break;  // kemb
    case 10: src = e_w2; break;
    case 11: src = c_w1; break;
    case 12: src = v_w1; break;
    case 13: src = n_w1; break;            // h half
    case 14: src = n_w1 + 64 * 64; break;  // nagg half
    default: src = n_w2; break;
  }
  u16* dst = W + m * 4096;
  for (int e = threadIdx.x; e < 4096; e += blockDim.x) {
    const int n = e >> 6, k = e & 63;
    dst[e] = f2bf(src[k * 64 + n]);
  }
}

__global__ __launch_bounds__(64 * WPB, 3) void egcl_mfma(
    const float* __restrict__ gh, const float* __restrict__ gcoord,
    const float* __restrict__ gvel, const u16* __restrict__ Wg,
    const float* __restrict__ e_w1, const float* __restrict__ e_b1,
    const float* __restrict__ e_b2,
    const float* __restrict__ n_b1, const float* __restrict__ n_b2,
    const float* __restrict__ c_b1, const float* __restrict__ c_w2,
    const float* __restrict__ v_b1, const float* __restrict__ v_w2,
    const float* __restrict__ v_b2,
    const float* __restrict__ ic_pat,
    const float* __restrict__ br_b1, const float* __restrict__ br_b2,
    const float* __restrict__ out_b,
    float* __restrict__ hout, float* __restrict__ cout, int B) {
  // 5120 u16 per wave: H[5][64]@0, K@320, T@1920, U@3520 (each [25][64] swz)
  __shared__ __align__(16) u16 arena[WPB][5120];

  const int t = threadIdx.x & 63;
  const int wv = threadIdx.x >> 6;
  const int g = blockIdx.x * WPB + wv;
  if (g >= B) return;  // waves independent; no block barriers anywhere

  u16* AR = arena[wv];
  u16* K_ = AR + 320;
  u16* T_ = AR + 1920;
  u16* U_ = AR + 3520;
  u16* EFa = T_;  // EF lives in T before T's first matmul use: [25][32] plain
  const int c15 = t & 15, q = t >> 4, q8 = q << 3;

  // ---------------- prologue: inputs ----------------
  float scvreg = 0.0f;
  if (t < 15) scvreg = gcoord[g * 15 + t];
  else if (t >= 16 && t < 31) scvreg = gvel[g * 15 + (t - 16)];

#pragma unroll
  for (int i = 0; i < 5; ++i) AR[uswz(i, t)] = f2bf(gh[(g * 5 + i) * HD + t]);

  // zero EF cols 12..31 (rows 0..24): 250 u32 slots
#pragma unroll
  for (int z = 0; z < 4; ++z) {
    const int e = t + z * 64;
    if (e < 250) {
      const int row = e / 10, cc = 12 + (e % 10) * 2;
      *reinterpret_cast<u32*>(EFa + row * 32 + cc) = 0u;
    }
  }

  float sqcc = 0.0f;  // squared coord-dist for this lane's tuple (radial)
  if (t < 25) {
    const int ti = t / 5, tj = t % 5;
    const float cix = __shfl(scvreg, ti * 3 + 0, 64), ciy = __shfl(scvreg, ti * 3 + 1, 64), ciz = __shfl(scvreg, ti * 3 + 2, 64);
    const float cjx = __shfl(scvreg, tj * 3 + 0, 64), cjy = __shfl(scvreg, tj * 3 + 1, 64), cjz = __shfl(scvreg, tj * 3 + 2, 64);
    const float vix = __shfl(scvreg, 16 + ti * 3 + 0, 64), viy = __shfl(scvreg, 16 + ti * 3 + 1, 64), viz = __shfl(scvreg, 16 + ti * 3 + 2, 64);
    const float vjx = __shfl(scvreg, 16 + tj * 3 + 0, 64), vjy = __shfl(scvreg, 16 + tj * 3 + 1, 64), vjz = __shfl(scvreg, 16 + tj * 3 + 2, 64);
    {
      const float dx = cix - cjx, dy = ciy - cjy, dz = ciz - cjz;
      sqcc = dx * dx + dy * dy + dz * dz;
    }
    auto sd = [](float sq) { return (sq > 0.0f) ? sqrtf(sq) : 0.0f; };
    float sq2;
    const float dcc = sd(sqcc);
    {
      const float dx = vix - vjx, dy = viy - vjy, dz = viz - vjz;
      sq2 = dx * dx + dy * dy + dz * dz;
    }
    const float dvv = sd(sq2);
    {
      const float dx = cix - vjx, dy = ciy - vjy, dz = ciz - vjz;
      sq2 = dx * dx + dy * dy + dz * dz;
    }
    const float dcv = sd(sq2);
    {
      const float dx = cjx - vix, dy = cjy - viy, dz = cjz - viz;
      sq2 = dx * dx + dy * dy + dz * dz;
    }
    const float dvc = sd(sq2);
    auto rbf3 = [&](float d, int base) {
      const float cut = (d <= 10.0f) ? (0.5f * (cosf(d * 0.31415926535897931f) + 1.0f)) : 0.0f;
      const float e = expf(-0.5f * d);
      const float u0 = e - 4.5399929762484854e-05f;
      const float u1 = e - 0.50002270f;
      const float u2 = e - 1.0f;
      const float BETA = 2.2502043f;
      EFa[t * 32 + base + 0] = f2bf((cut * expf(-BETA * u0 * u0) - 0.05f) * (1.0f / 0.15f));
      EFa[t * 32 + base + 1] = f2bf((cut * expf(-BETA * u1 * u1) - 0.05f) * (1.0f / 0.15f));
      EFa[t * 32 + base + 2] = f2bf((cut * expf(-BETA * u2 * u2) - 0.05f) * (1.0f / 0.15f));
    };
    rbf3(dcc, 0);
    rbf3(dvv, 3);
    rbf3(dcv, 6);
    rbf3(dvc, 9);
  }

  f32x4 acc[2][4];
  float svv[4];
  float svc[2][4];

  // ---------------- kemb = (ef @ ic_wef) * ic_pat[pattern] -> K ------------
  {
#pragma unroll
    for (int mt = 0; mt < 2; ++mt)
#pragma unroll
      for (int nt = 0; nt < 4; ++nt) acc[mt][nt] = (f32x4){0.f, 0.f, 0.f, 0.f};
    const u16* WTp = Wg + 16 * 4096;
    short8 bfr[4];
#pragma unroll
    for (int nt = 0; nt < 4; ++nt)
      bfr[nt] = *reinterpret_cast<const short8*>(WTp + (nt * 16 + c15) * 32 + q8);
#pragma unroll
    for (int mt = 0; mt < 2; ++mt) {
      int row = mt * 16 + c15;
      row = row > 24 ? 24 : row;
      const short8 a = *reinterpret_cast<const short8*>(EFa + row * 32 + q8);
#pragma unroll
      for (int nt = 0; nt < 4; ++nt)
        acc[mt][nt] = __builtin_amdgcn_mfma_f32_16x16x32_bf16(a, bfr[nt], acc[mt][nt], 0, 0, 0);
    }
#pragma unroll
    for (int nt = 0; nt < 4; ++nt) {
      const int col = nt * 16 + c15;
      const float p1 = ic_pat[64 + col], p2 = ic_pat[128 + col];
#pragma unroll
      for (int mt = 0; mt < 2; ++mt)
#pragma unroll
        for (int i = 0; i < 4; ++i) {
          const int row = mt * 16 + q * 4 + i;
          if (row < 25) {
            const bool diag = (row % 6) == 0;  // tuples 0,6,12,18,24
            K_[uswz(row, col)] = f2bf(acc[mt][nt][i] * (diag ? p2 : p1));
          }
        }
    }
  }

  // ---------------- descriptor-driven phase loop ----------------
#pragma unroll 1
  for (int ph = 0; ph < 16; ++ph) {
    const u32 d = PHT[ph];
    const int widx = d & 31;
    const int asel = (d >> 5) & 3;
    const int dsel = (d >> 7) & 3;
    const int mtn = ((d >> 9) & 1) + 1;
    const int epi = (d >> 10) & 7;
    const int bsel = (d >> 13) & 15;
    const int post = (d >> 17) & 7;
    const int rmax = (mtn == 2) ? 24 : 4;
    const int rowlim = (mtn == 2) ? 25 : 5;
    const u16* A_ = AR + (asel == 0 ? 0 : asel == 1 ? 320 : asel == 2 ? 1920 : 3520);
    u16* D_ = AR + (dsel == 0 ? 0 : dsel == 1 ? 320 : dsel == 2 ? 1920 : 3520) +
              (((d >> 21) & 1) << 9);

    // bias (vector-per-col); loaded early so latency hides under MFMAs
    const float* bp = nullptr;
    switch (bsel) {
      case 1: bp = br_b1; break;
      case 2: bp = br_b1 + 64; break;
      case 3: bp = br_b1 + 128; break;
      case 4: bp = br_b2; break;
      case 5: bp = br_b2 + 64; break;
      case 6: bp = br_b2 + 128; break;
      case 7: bp = out_b; break;
      case 8: bp = e_b2; break;
      case 9: bp = n_b1; break;
      case 10: bp = n_b2; break;
      default: break;
    }
    float bb[4] = {0.f, 0.f, 0.f, 0.f};
    if (bp) {
#pragma unroll
      for (int nt = 0; nt < 4; ++nt) bb[nt] = bp[nt * 16 + c15];
    }

    // B fragments
    const u16* WTp = Wg + (widx << 12);
    short8 bfr[4][2];
#pragma unroll
    for (int nt = 0; nt < 4; ++nt)
#pragma unroll
      for (int s = 0; s < 2; ++s)
        bfr[nt][s] = *reinterpret_cast<const short8*>(WTp + (nt * 16 + c15) * 64 + s * 32 + q8);

    if (!((d >> 20) & 1)) {
#pragma unroll
      for (int mt = 0; mt < 2; ++mt)
#pragma unroll
        for (int nt = 0; nt < 4; ++nt) acc[mt][nt] = (f32x4){0.f, 0.f, 0.f, 0.f};
    }

#pragma unroll
    for (int mt = 0; mt < 2; ++mt) {
      if (mt < mtn) {
        int row = mt * 16 + c15;
        row = row > rmax ? rmax : row;
        const int idx = ((row << 6) | q8) ^ ((row & 7) << 3);
        const short8 a0 = *reinterpret_cast<const short8*>(A_ + idx);
        const short8 a1 = *reinterpret_cast<const short8*>(A_ + (idx ^ 32));
#pragma unroll
        for (int nt = 0; nt < 4; ++nt)
          acc[mt][nt] = __builtin_amdgcn_mfma_f32_16x16x32_bf16(a0, bfr[nt][0], acc[mt][nt], 0, 0, 0);
#pragma unroll
        for (int nt = 0; nt < 4; ++nt)
          acc[mt][nt] = __builtin_amdgcn_mfma_f32_16x16x32_bf16(a1, bfr[nt][1], acc[mt][nt], 0, 0, 0);
      }
    }

    // ---- epilogue ----
    switch (epi) {
      case 1:
      case 2: {  // store / relu+bias
        const bool dorelu = (epi == 2);
#pragma unroll
        for (int nt = 0; nt < 4; ++nt) {
          const int col = nt * 16 + c15;
#pragma unroll
          for (int mt = 0; mt < 2; ++mt)
            if (mt < mtn)
#pragma unroll
              for (int i = 0; i < 4; ++i) {
                const int row = mt * 16 + q * 4 + i;
                if (row < rowlim) {
                  float v = acc[mt][nt][i] + bb[nt];
                  if (dorelu) v = fmaxf(v, 0.0f);
                  D_[uswz(row, col)] = f2bf(v);
                }
              }
        }
      } break;
      case 3: {  // MULT: D = relu(acc+b) * U (elementwise)
#pragma unroll
        for (int nt = 0; nt < 4; ++nt) {
          const int col = nt * 16 + c15;
#pragma unroll
          for (int mt = 0; mt < 2; ++mt)
#pragma unroll
            for (int i = 0; i < 4; ++i) {
              const int row = mt * 16 + q * 4 + i;
              if (row < 25) {
                const int ix = uswz(row, col);
                const float sv = fmaxf(acc[mt][nt][i] + bb[nt], 0.0f);
                D_[ix] = f2bf(sv * bf2f(U_[ix]));
              }
            }
        }
      } break;
      case 4: {  // RESID: D += relu(acc+b)
#pragma unroll
        for (int nt = 0; nt < 4; ++nt) {
          const int col = nt * 16 + c15;
#pragma unroll
          for (int mt = 0; mt < 2; ++mt)
#pragma unroll
            for (int i = 0; i < 4; ++i) {
              const int row = mt * 16 + q * 4 + i;
              if (row < 25) {
                const int ix = uswz(row, col);
                D_[ix] = f2bf(fmaxf(acc[mt][nt][i] + bb[nt], 0.0f) + bf2f(D_[ix]));
              }
            }
        }
      } break;
      case 5: {  // VRED: v-model reduction -> svv
#pragma unroll
        for (int i = 0; i < 4; ++i) {
          float s = 0.0f;
#pragma unroll
          for (int nt = 0; nt < 4; ++nt) {
            const int col = nt * 16 + c15;
            s += fmaxf(acc[0][nt][i] + v_b1[col], 0.0f) * v_w2[col];
          }
          s += __shfl_xor(s, 1, 64);
          s += __shfl_xor(s, 2, 64);
          s += __shfl_xor(s, 4, 64);
          s += __shfl_xor(s, 8, 64);
          svv[i] = s;
        }
      } break;
      case 6: {  // CRED: c-model reduction -> svc
#pragma unroll
        for (int mt = 0; mt < 2; ++mt)
#pragma unroll
          for (int i = 0; i < 4; ++i) {
            float s = 0.0f;
#pragma unroll
            for (int nt = 0; nt < 4; ++nt) {
              const int col = nt * 16 + c15;
              s += fmaxf(acc[mt][nt][i] + c_b1[col], 0.0f) * c_w2[col];
            }
            s += __shfl_xor(s, 1, 64);
            s += __shfl_xor(s, 2, 64);
            s += __shfl_xor(s, 4, 64);
            s += __shfl_xor(s, 8, 64);
            svc[mt][i] = s;
          }
      } break;
      case 7: {  // HOUT: hout = gh + acc + n_b2
#pragma unroll
        for (int nt = 0; nt < 4; ++nt) {
          const int col = nt * 16 + c15;
#pragma unroll
          for (int i = 0; i < 4; ++i) {
            const int row = q * 4 + i;
            if (row < 5) {
              const size_t ix = (size_t)(g * 5 + row) * HD + col;
              hout[ix] = gh[ix] + acc[0][nt][i] + bb[nt];
            }
          }
        }
      } break;
      default: break;  // skip (P13)
    }

    // ---- post ops (one copy each) ----
    switch (post) {
      case 1: {  // EINSUM: mult = k0(U) @ k1(T) per channel -> U
        float mu[25];
#pragma unroll
        for (int p = 0; p < 25; ++p) mu[p] = 0.0f;
#pragma unroll
        for (int j = 0; j < 5; ++j) {
          float k1r[5], k0c[5];
#pragma unroll
          for (int k = 0; k < 5; ++k) k1r[k] = bf2f(T_[uswz(j * 5 + k, t)]);
#pragma unroll
          for (int i = 0; i < 5; ++i) k0c[i] = bf2f(U_[uswz(i * 5 + j, t)]);
#pragma unroll
          for (int i = 0; i < 5; ++i)
#pragma unroll
            for (int k = 0; k < 5; ++k) mu[i * 5 + k] = fmaf(k0c[i], k1r[k], mu[i * 5 + k]);
        }
#pragma unroll
        for (int p = 0; p < 25; ++p) U_[uswz(p, t)] = f2bf(mu[p]);
      } break;
      case 2: {  // EDGEASM: edge pre-act -> T rows 0-19
        float aAc[5], aBc[5];
#pragma unroll
        for (int i = 0; i < 5; ++i) {
          aAc[i] = bf2f(U_[uswz(i, t)]);
          aBc[i] = bf2f(U_[uswz(8 + i, t)]);
        }
        const float eb1v = e_b1[t];
        const float wradv = e_w1[128 * HD + t];
        float ec[20];
#pragma unroll
        for (int p = 0; p < 20; ++p) {
          const int i = p >> 2, jj = p & 3;
          const int j = jj + (jj >= i ? 1 : 0);
          const float radial = rlane(sqcc, i * 5 + j);
          const float cc = bf2f(T_[uswz(i * 5 + j, t)]);
          ec[p] = fmaxf(aAc[i] + aBc[j] + radial * wradv + cc + eb1v, 0.0f);
        }
#pragma unroll
        for (int p = 0; p < 20; ++p) T_[uswz(p, t)] = f2bf(ec[p]);
      } break;
      case 3: {  // NAGG: segment-sum edge_feat(U) -> K rows 0-4
#pragma unroll
        for (int i = 0; i < 5; ++i) {
          float na = 0.0f;
#pragma unroll
          for (int jj = 0; jj < 4; ++jj) na += bf2f(U_[uswz(4 * i + jj, t)]);
          K_[uswz(i, t)] = f2bf(na);
        }
      } break;
      case 4: {  // COORD: coord update + cout write
        const float vb2 = v_b2[0];
        float coutreg = 0.0f;
#pragma unroll
        for (int i = 0; i < 5; ++i) {
          const float vmi = rlane(svv[i & 3], (i >> 2) << 4) + vb2;
#pragma unroll
          for (int dd = 0; dd < 3; ++dd) {
            const float ci = rlane(scvreg, i * 3 + dd);
            float s = 0.0f;
#pragma unroll
            for (int jj = 0; jj < 4; ++jj) {
              const int j = jj + (jj >= i ? 1 : 0);
              const int p = i * 4 + jj;
              const float cmp = rlane(svc[p >> 4][p & 3], ((p & 15) >> 2) << 4);
              float tr = (ci - rlane(scvreg, j * 3 + dd)) * cmp;
              tr = fminf(fmaxf(tr, -100.0f), 100.0f);
              s += tr;
            }
            const float val = ci + 0.25f * s + rlane(scvreg, 16 + i * 3 + dd) * vmi;
            if (t == i * 3 + dd) coutreg = val;
          }
        }
        if (t < 15) cout[g * 15 + t] = coutreg;
      } break;
      default: break;
    }
  }
}

extern "C" void kernel_launch(void* const* d_in, const int* in_sizes, int n_in,
                              void* d_out, int out_size, void* d_ws, size_t ws_size,
                              hipStream_t stream) {
  if (n_in < 27) return;
  const float* gh    = (const float*)d_in[0];
  const float* coord = (const float*)d_in[1];
  const float* vel   = (const float*)d_in[2];
  const float* e_w1 = (const float*)d_in[4];
  const float* e_b1 = (const float*)d_in[5];
  const float* e_w2 = (const float*)d_in[6];
  const float* e_b2 = (const float*)d_in[7];
  const float* n_w1 = (const float*)d_in[8];
  const float* n_b1 = (const float*)d_in[9];
  const float* n_w2 = (const float*)d_in[10];
  const float* n_b2 = (const float*)d_in[11];
  const float* c_w1 = (const float*)d_in[12];
  const float* c_b1 = (const float*)d_in[13];
  const float* c_w2 = (const float*)d_in[14];
  const float* v_w1 = (const float*)d_in[15];
  const float* v_b1 = (const float*)d_in[16];
  const float* v_w2 = (const float*)d_in[17];
  const float* v_b2 = (const float*)d_in[18];
  const float* ic_wef = (const float*)d_in[19];
  const float* ic_pat = (const float*)d_in[20];
  const float* br_w1 = (const float*)d_in[21];
  const float* br_b1 = (const float*)d_in[22];
  const float* br_w2 = (const float*)d_in[23];
  const float* br_b2 = (const float*)d_in[24];
  const float* out_w = (const float*)d_in[25];
  const float* out_b = (const float*)d_in[26];

  const int N = in_sizes[0] / HD;  // 100000
  const int B = N / 5;             // 20000 graphs
  float* hout = (float*)d_out;
  float* cout = (float*)d_out + (size_t)N * HD;
  u16* W = (u16*)d_ws;  // 16*4096 + 2048 u16 = 135168 B

  prepack<<<17, 256, 0, stream>>>(br_w1, br_w2, out_w, e_w1, e_w2, c_w1, v_w1,
                                  n_w1, n_w2, ic_wef, W);

  const int blocks = (B + WPB - 1) / WPB;
  egcl_mfma<<<blocks, 64 * WPB, 0, stream>>>(
      gh, coord, vel, W, e_w1, e_b1, e_b2, n_b1, n_b2, c_b1, c_w2, v_b1, v_w2,
      v_b2, ic_pat, br_b1, br_b2, out_b, hout, cout, B);
}

// Round 7
// 330.086 us; speedup vs baseline: 1.7669x; 1.4150x over previous
//
#include <hip/hip_runtime.h>
#include <math.h>

#define HD 64
#define WPB 2

typedef unsigned short u16;
typedef unsigned int u32;
typedef __attribute__((ext_vector_type(8))) short short8;
typedef __attribute__((ext_vector_type(4))) float f32x4;

__device__ __forceinline__ u16 f2bf(float f) {
  return (u16)((__float_as_uint(f) + 0x8000u) >> 16);  // round-half-up
}
__device__ __forceinline__ float bf2f(u16 x) {
  return __uint_as_float(((u32)x) << 16);
}
__device__ __forceinline__ int uswz(int row, int col) {
  return ((row << 6) | col) ^ ((row & 7) << 3);
}
__device__ __forceinline__ float rlane(float v, int l) {
  return __uint_as_float(__builtin_amdgcn_readlane(__float_as_uint(v), l));
}

// No explicit LDS fences: all LDS traffic is wave-private and compiler-visible
// (validated R4/R6: absmax stable). Hoisted A-reads precede all same-buffer
// writes, so in-place phases are safe by program order.

// read A fragments once per phase (rows clamped to RMAX)
template <int MT, int RMAX>
__device__ __forceinline__ void loadA(const u16* A_, int t, short8* a0, short8* a1) {
  const int q8 = (t >> 4) << 3;
#pragma unroll
  for (int mt = 0; mt < MT; ++mt) {
    int row = mt * 16 + (t & 15);
    row = row > RMAX ? RMAX : row;
    const int idx = ((row << 6) | q8) ^ ((row & 7) << 3);
    a0[mt] = *reinterpret_cast<const short8*>(A_ + idx);
    a1[mt] = *reinterpret_cast<const short8*>(A_ + (idx ^ 32));
  }
}

// one N-half (cols nh*32..nh*32+31) of the 64x64 matmul
template <int MT>
__device__ __forceinline__ void mmh(const short8* a0, const short8* a1,
                                    const u16* __restrict__ WT, f32x4 (*acc)[2],
                                    int t, int nh) {
  const int c15 = t & 15;
  const int q8 = (t >> 4) << 3;
  short8 b[2][2];
#pragma unroll
  for (int n2 = 0; n2 < 2; ++n2) {
    const int nt = nh * 2 + n2;
#pragma unroll
    for (int s = 0; s < 2; ++s)
      b[n2][s] = *reinterpret_cast<const short8*>(WT + (nt * 16 + c15) * 64 + s * 32 + q8);
  }
#pragma unroll
  for (int mt = 0; mt < MT; ++mt) {
#pragma unroll
    for (int n2 = 0; n2 < 2; ++n2)
      acc[mt][n2] = __builtin_amdgcn_mfma_f32_16x16x32_bf16(a0[mt], b[n2][0], acc[mt][n2], 0, 0, 0);
#pragma unroll
    for (int n2 = 0; n2 < 2; ++n2)
      acc[mt][n2] = __builtin_amdgcn_mfma_f32_16x16x32_bf16(a1[mt], b[n2][1], acc[mt][n2], 0, 0, 0);
  }
}

// EPI: 1=store(+bias), 2=relu(+bias), 3=relu*M (MULT), 4=relu + D (RESID)
template <int MT, int RMAX, int EPI>
__device__ __forceinline__ void run_phase(const u16* A_, u16* D_, const u16* M_,
                                          const u16* __restrict__ WT,
                                          const float* __restrict__ bias, int t,
                                          int rowoff = 0) {
  const int c15 = t & 15, q = t >> 4;
  constexpr int rowlim = (MT == 2) ? 25 : 5;
  short8 a0[MT], a1[MT];
  loadA<MT, RMAX>(A_, t, a0, a1);
#pragma unroll
  for (int nh = 0; nh < 2; ++nh) {
    f32x4 acc[MT][2];
#pragma unroll
    for (int mt = 0; mt < MT; ++mt)
#pragma unroll
      for (int n2 = 0; n2 < 2; ++n2) acc[mt][n2] = (f32x4){0.f, 0.f, 0.f, 0.f};
    mmh<MT>(a0, a1, WT, acc, t, nh);
#pragma unroll
    for (int n2 = 0; n2 < 2; ++n2) {
      const int col = (nh * 2 + n2) * 16 + c15;
      const float bb = bias ? bias[col] : 0.0f;
#pragma unroll
      for (int mt = 0; mt < MT; ++mt)
#pragma unroll
        for (int i = 0; i < 4; ++i) {
          const int row = mt * 16 + q * 4 + i;
          if (row < rowlim) {
            const int ix = uswz(row + rowoff, col);
            float v = acc[mt][n2][i] + bb;
            if (EPI >= 2) v = fmaxf(v, 0.0f);
            if (EPI == 3) v *= bf2f(M_[ix]);
            if (EPI == 4) v += bf2f(D_[ix]);
            D_[ix] = f2bf(v);
          }
        }
    }
  }
}

// ---- pre-pass: pack weights to bf16 transposed [n][k] ----
__global__ __launch_bounds__(256) void prepack(
    const float* __restrict__ br_w1, const float* __restrict__ br_w2,
    const float* __restrict__ out_w, const float* __restrict__ e_w1,
    const float* __restrict__ e_w2, const float* __restrict__ c_w1,
    const float* __restrict__ v_w1, const float* __restrict__ n_w1,
    const float* __restrict__ n_w2, const float* __restrict__ ic_wef,
    u16* __restrict__ W) {
  const int m = blockIdx.x;
  if (m == 16) {  // ic_wef^T, K padded 12->32 with zeros
    for (int e = threadIdx.x; e < 2048; e += blockDim.x) {
      const int n = e >> 5, k = e & 31;
      W[16 * 4096 + e] = (k < 12) ? f2bf(ic_wef[k * 64 + n]) : (u16)0;
    }
    return;
  }
  const float* src;
  switch (m) {
    case 0: src = br_w1; break;
    case 1: src = br_w1 + 4096; break;
    case 2: src = br_w1 + 8192; break;
    case 3: src = br_w2; break;
    case 4: src = br_w2 + 4096; break;
    case 5: src = br_w2 + 8192; break;
    case 6: src = out_w; break;
    case 7: src = e_w1; break;             // h[row]
    case 8: src = e_w1 + 64 * 64; break;   // h[col]
    case 9: src = e_w1 + 129 * 64; break;  // kemb
    case 10: src = e_w2; break;
    case 11: src = c_w1; break;
    case 12: src = v_w1; break;
    case 13: src = n_w1; break;            // h half
    case 14: src = n_w1 + 64 * 64; break;  // nagg half
    default: src = n_w2; break;
  }
  u16* dst = W + m * 4096;
  for (int e = threadIdx.x; e < 4096; e += blockDim.x) {
    const int n = e >> 6, k = e & 63;
    dst[e] = f2bf(src[k * 64 + n]);
  }
}

__global__ __launch_bounds__(64 * WPB, 4) void egcl_mfma(
    const float* __restrict__ gh, const float* __restrict__ gcoord,
    const float* __restrict__ gvel, const u16* __restrict__ Wg,
    const float* __restrict__ e_w1, const float* __restrict__ e_b1,
    const float* __restrict__ e_b2,
    const float* __restrict__ n_b1, const float* __restrict__ n_b2,
    const float* __restrict__ c_b1, const float* __restrict__ c_w2,
    const float* __restrict__ v_b1, const float* __restrict__ v_w2,
    const float* __restrict__ v_b2,
    const float* __restrict__ ic_pat,
    const float* __restrict__ br_b1, const float* __restrict__ br_b2,
    const float* __restrict__ out_b,
    float* __restrict__ hout, float* __restrict__ cout, int B) {
  // 5120 u16 per wave: H[5][64]@0, K@320, T@1920, U@3520 (each [25][64] swz)
  __shared__ __align__(16) u16 arena[WPB][5120];

  const int t = threadIdx.x & 63;
  const int wv = threadIdx.x >> 6;
  const int g = blockIdx.x * WPB + wv;
  if (g >= B) return;  // waves independent; no block barriers anywhere

  u16* AR = arena[wv];
  u16* H_ = AR;
  u16* K_ = AR + 320;
  u16* T_ = AR + 1920;
  u16* U_ = AR + 3520;
  u16* EFa = T_;  // EF lives in T before T's first matmul use: [25][32] plain
  const int c15 = t & 15, q = t >> 4, q8 = q << 3;
#define WT(m) (Wg + (m) * 4096)

  // ---------------- prologue: inputs ----------------
  float scvreg = 0.0f;
  if (t < 15) scvreg = gcoord[g * 15 + t];
  else if (t >= 16 && t < 31) scvreg = gvel[g * 15 + (t - 16)];

#pragma unroll
  for (int i = 0; i < 5; ++i) H_[uswz(i, t)] = f2bf(gh[(g * 5 + i) * HD + t]);

  // zero EF cols 12..31 (rows 0..24): 250 u32 slots
#pragma unroll
  for (int z = 0; z < 4; ++z) {
    const int e = t + z * 64;
    if (e < 250) {
      const int row = e / 10, cc = 12 + (e % 10) * 2;
      *reinterpret_cast<u32*>(EFa + row * 32 + cc) = 0u;
    }
  }

  float sqcc = 0.0f;  // squared coord-dist for this lane's tuple (radial)
  if (t < 25) {
    const int ti = t / 5, tj = t % 5;
    const float cix = __shfl(scvreg, ti * 3 + 0, 64), ciy = __shfl(scvreg, ti * 3 + 1, 64), ciz = __shfl(scvreg, ti * 3 + 2, 64);
    const float cjx = __shfl(scvreg, tj * 3 + 0, 64), cjy = __shfl(scvreg, tj * 3 + 1, 64), cjz = __shfl(scvreg, tj * 3 + 2, 64);
    const float vix = __shfl(scvreg, 16 + ti * 3 + 0, 64), viy = __shfl(scvreg, 16 + ti * 3 + 1, 64), viz = __shfl(scvreg, 16 + ti * 3 + 2, 64);
    const float vjx = __shfl(scvreg, 16 + tj * 3 + 0, 64), vjy = __shfl(scvreg, 16 + tj * 3 + 1, 64), vjz = __shfl(scvreg, 16 + tj * 3 + 2, 64);
    {
      const float dx = cix - cjx, dy = ciy - cjy, dz = ciz - cjz;
      sqcc = dx * dx + dy * dy + dz * dz;
    }
    auto sd = [](float sq) { return (sq > 0.0f) ? sqrtf(sq) : 0.0f; };
    float sq2;
    const float dcc = sd(sqcc);
    {
      const float dx = vix - vjx, dy = viy - vjy, dz = viz - vjz;
      sq2 = dx * dx + dy * dy + dz * dz;
    }
    const float dvv = sd(sq2);
    {
      const float dx = cix - vjx, dy = ciy - vjy, dz = ciz - vjz;
      sq2 = dx * dx + dy * dy + dz * dz;
    }
    const float dcv = sd(sq2);
    {
      const float dx = cjx - vix, dy = cjy - viy, dz = cjz - viz;
      sq2 = dx * dx + dy * dy + dz * dz;
    }
    const float dvc = sd(sq2);
    auto rbf3 = [&](float d, int base) {
      const float cut = (d <= 10.0f) ? (0.5f * (cosf(d * 0.31415926535897931f) + 1.0f)) : 0.0f;
      const float e = expf(-0.5f * d);
      const float u0 = e - 4.5399929762484854e-05f;
      const float u1 = e - 0.50002270f;
      const float u2 = e - 1.0f;
      const float BETA = 2.2502043f;
      EFa[t * 32 + base + 0] = f2bf((cut * expf(-BETA * u0 * u0) - 0.05f) * (1.0f / 0.15f));
      EFa[t * 32 + base + 1] = f2bf((cut * expf(-BETA * u1 * u1) - 0.05f) * (1.0f / 0.15f));
      EFa[t * 32 + base + 2] = f2bf((cut * expf(-BETA * u2 * u2) - 0.05f) * (1.0f / 0.15f));
    };
    rbf3(dcc, 0);
    rbf3(dvv, 3);
    rbf3(dcv, 6);
    rbf3(dvc, 9);
  }

  // ---------------- kemb = (ef @ ic_wef) * ic_pat[pattern] -> K ------------
  {
    short8 aE[2];
#pragma unroll
    for (int mt = 0; mt < 2; ++mt) {
      int row = mt * 16 + c15;
      row = row > 24 ? 24 : row;
      aE[mt] = *reinterpret_cast<const short8*>(EFa + row * 32 + q8);
    }
    const u16* WTp = Wg + 16 * 4096;
#pragma unroll
    for (int nh = 0; nh < 2; ++nh) {
      f32x4 acc[2][2];
#pragma unroll
      for (int mt = 0; mt < 2; ++mt)
#pragma unroll
        for (int n2 = 0; n2 < 2; ++n2) acc[mt][n2] = (f32x4){0.f, 0.f, 0.f, 0.f};
      short8 b[2];
#pragma unroll
      for (int n2 = 0; n2 < 2; ++n2)
        b[n2] = *reinterpret_cast<const short8*>(WTp + ((nh * 2 + n2) * 16 + c15) * 32 + q8);
#pragma unroll
      for (int mt = 0; mt < 2; ++mt)
#pragma unroll
        for (int n2 = 0; n2 < 2; ++n2)
          acc[mt][n2] = __builtin_amdgcn_mfma_f32_16x16x32_bf16(aE[mt], b[n2], acc[mt][n2], 0, 0, 0);
#pragma unroll
      for (int n2 = 0; n2 < 2; ++n2) {
        const int col = (nh * 2 + n2) * 16 + c15;
        const float p1 = ic_pat[64 + col], p2 = ic_pat[128 + col];
#pragma unroll
        for (int mt = 0; mt < 2; ++mt)
#pragma unroll
          for (int i = 0; i < 4; ++i) {
            const int row = mt * 16 + q * 4 + i;
            if (row < 25) {
              const bool diag = (row % 6) == 0;  // tuples 0,6,12,18,24
              K_[uswz(row, col)] = f2bf(acc[mt][n2][i] * (diag ? p2 : p1));
            }
          }
      }
    }
  }

  float svv[4];
  float svc[2][4];

  // ---------------- branch MLPs ----------------
  run_phase<2, 24, 2>(K_, T_, nullptr, WT(1), br_b1 + 64, t);    // k0 L1 -> T
  run_phase<2, 24, 2>(T_, U_, nullptr, WT(4), br_b2 + 64, t);    // k0 -> U
  run_phase<2, 24, 2>(K_, T_, nullptr, WT(2), br_b1 + 128, t);   // k1 L1 -> T
  run_phase<2, 24, 2>(T_, T_, nullptr, WT(5), br_b2 + 128, t);   // k1 -> T (in-place)

  // ---------------- einsum (col mode, j-outer) : mult -> U ----------------
  {
    float mu[25];
#pragma unroll
    for (int p = 0; p < 25; ++p) mu[p] = 0.0f;
#pragma unroll
    for (int j = 0; j < 5; ++j) {
      float k1r[5], k0c[5];
#pragma unroll
      for (int k = 0; k < 5; ++k) k1r[k] = bf2f(T_[uswz(j * 5 + k, t)]);
#pragma unroll
      for (int i = 0; i < 5; ++i) k0c[i] = bf2f(U_[uswz(i * 5 + j, t)]);
#pragma unroll
      for (int i = 0; i < 5; ++i)
#pragma unroll
        for (int k = 0; k < 5; ++k) mu[i * 5 + k] = fmaf(k0c[i], k1r[k], mu[i * 5 + k]);
    }
#pragma unroll
    for (int p = 0; p < 25; ++p) U_[uswz(p, t)] = f2bf(mu[p]);
  }

  run_phase<2, 24, 2>(K_, T_, nullptr, WT(0), br_b1, t);         // sm L1 -> T
  run_phase<2, 24, 3>(T_, T_, U_, WT(3), br_b2, t);              // z = relu(sm)*mult -> T
  run_phase<2, 24, 4>(T_, K_, nullptr, WT(6), out_b, t);         // residual -> K
  run_phase<2, 24, 1>(K_, T_, nullptr, WT(9), nullptr, t);       // accC -> T
  run_phase<1, 4, 1>(H_, U_, nullptr, WT(7), nullptr, t);        // accA -> U rows0-4
  run_phase<1, 4, 1>(H_, U_, nullptr, WT(8), nullptr, t, 8);     // accB -> U rows8-12

  // ---------------- v-model (VRED) ----------------
  {
    short8 a0[1], a1[1];
    loadA<1, 4>(H_, t, a0, a1);
    float s[4] = {0.f, 0.f, 0.f, 0.f};
#pragma unroll
    for (int nh = 0; nh < 2; ++nh) {
      f32x4 acc[1][2];
      acc[0][0] = (f32x4){0.f, 0.f, 0.f, 0.f};
      acc[0][1] = (f32x4){0.f, 0.f, 0.f, 0.f};
      mmh<1>(a0, a1, WT(12), acc, t, nh);
#pragma unroll
      for (int n2 = 0; n2 < 2; ++n2) {
        const int col = (nh * 2 + n2) * 16 + c15;
        const float b1v = v_b1[col], w2v = v_w2[col];
#pragma unroll
        for (int i = 0; i < 4; ++i) s[i] += fmaxf(acc[0][n2][i] + b1v, 0.0f) * w2v;
      }
    }
#pragma unroll
    for (int i = 0; i < 4; ++i) {
      float ss = s[i];
      ss += __shfl_xor(ss, 1, 64);
      ss += __shfl_xor(ss, 2, 64);
      ss += __shfl_xor(ss, 4, 64);
      ss += __shfl_xor(ss, 8, 64);
      svv[i] = ss;
    }
  }

  // ---------------- edge assembly (col mode) ----------------
  {
    float aAc[5], aBc[5];
#pragma unroll
    for (int i = 0; i < 5; ++i) {
      aAc[i] = bf2f(U_[uswz(i, t)]);
      aBc[i] = bf2f(U_[uswz(8 + i, t)]);
    }
    const float eb1v = e_b1[t];
    const float wradv = e_w1[128 * HD + t];
    float ec[20];
#pragma unroll
    for (int p = 0; p < 20; ++p) {
      const int i = p >> 2, jj = p & 3;
      const int j = jj + (jj >= i ? 1 : 0);
      const float radial = rlane(sqcc, i * 5 + j);
      const float cc = bf2f(T_[uswz(i * 5 + j, t)]);
      ec[p] = fmaxf(aAc[i] + aBc[j] + radial * wradv + cc + eb1v, 0.0f);
    }
#pragma unroll
    for (int p = 0; p < 20; ++p) T_[uswz(p, t)] = f2bf(ec[p]);
  }

  run_phase<2, 24, 2>(T_, U_, nullptr, WT(10), e_b2, t);         // edge_feat -> U

  // ---------------- nagg -> K rows 0-4 ----------------
#pragma unroll
  for (int i = 0; i < 5; ++i) {
    float na = 0.0f;
#pragma unroll
    for (int jj = 0; jj < 4; ++jj) na += bf2f(U_[uswz(4 * i + jj, t)]);
    K_[uswz(i, t)] = f2bf(na);
  }

  // ---------------- c-model (CRED) ----------------
  {
    short8 a0[2], a1[2];
    loadA<2, 24>(U_, t, a0, a1);
    float s[2][4] = {{0.f, 0.f, 0.f, 0.f}, {0.f, 0.f, 0.f, 0.f}};
#pragma unroll
    for (int nh = 0; nh < 2; ++nh) {
      f32x4 acc[2][2];
#pragma unroll
      for (int mt = 0; mt < 2; ++mt)
#pragma unroll
        for (int n2 = 0; n2 < 2; ++n2) acc[mt][n2] = (f32x4){0.f, 0.f, 0.f, 0.f};
      mmh<2>(a0, a1, WT(11), acc, t, nh);
#pragma unroll
      for (int n2 = 0; n2 < 2; ++n2) {
        const int col = (nh * 2 + n2) * 16 + c15;
        const float b1v = c_b1[col], w2v = c_w2[col];
#pragma unroll
        for (int mt = 0; mt < 2; ++mt)
#pragma unroll
          for (int i = 0; i < 4; ++i)
            s[mt][i] += fmaxf(acc[mt][n2][i] + b1v, 0.0f) * w2v;
      }
    }
#pragma unroll
    for (int mt = 0; mt < 2; ++mt)
#pragma unroll
      for (int i = 0; i < 4; ++i) {
        float ss = s[mt][i];
        ss += __shfl_xor(ss, 1, 64);
        ss += __shfl_xor(ss, 2, 64);
        ss += __shfl_xor(ss, 4, 64);
        ss += __shfl_xor(ss, 8, 64);
        svc[mt][i] = ss;
      }
  }

  // ---------------- coord output (VALU only) ----------------
  {
    const float vb2 = v_b2[0];
    float coutreg = 0.0f;
#pragma unroll
    for (int i = 0; i < 5; ++i) {
      const float vmi = rlane(svv[i & 3], (i >> 2) << 4) + vb2;
#pragma unroll
      for (int dd = 0; dd < 3; ++dd) {
        const float ci = rlane(scvreg, i * 3 + dd);
        float s = 0.0f;
#pragma unroll
        for (int jj = 0; jj < 4; ++jj) {
          const int j = jj + (jj >= i ? 1 : 0);
          const int p = i * 4 + jj;
          const float cmp = rlane(svc[p >> 4][p & 3], ((p & 15) >> 2) << 4);
          float tr = (ci - rlane(scvreg, j * 3 + dd)) * cmp;
          tr = fminf(fmaxf(tr, -100.0f), 100.0f);
          s += tr;
        }
        const float val = ci + 0.25f * s + rlane(scvreg, 16 + i * 3 + dd) * vmi;
        if (t == i * 3 + dd) coutreg = val;
      }
    }
    if (t < 15) cout[g * 15 + t] = coutreg;
  }

  // ---------------- node model: L1 = relu(H@W13 + nagg@W14 + n_b1) -> T ----
  {
    short8 a0h[1], a1h[1], a0k[1], a1k[1];
    loadA<1, 4>(H_, t, a0h, a1h);
    loadA<1, 4>(K_, t, a0k, a1k);
#pragma unroll
    for (int nh = 0; nh < 2; ++nh) {
      f32x4 acc[1][2];
      acc[0][0] = (f32x4){0.f, 0.f, 0.f, 0.f};
      acc[0][1] = (f32x4){0.f, 0.f, 0.f, 0.f};
      mmh<1>(a0h, a1h, WT(13), acc, t, nh);
      mmh<1>(a0k, a1k, WT(14), acc, t, nh);
#pragma unroll
      for (int n2 = 0; n2 < 2; ++n2) {
        const int col = (nh * 2 + n2) * 16 + c15;
        const float nb = n_b1[col];
#pragma unroll
        for (int i = 0; i < 4; ++i) {
          const int row = q * 4 + i;
          if (row < 5) T_[uswz(row, col)] = f2bf(fmaxf(acc[0][n2][i] + nb, 0.0f));
        }
      }
    }
  }

  // ---------------- node model L2 + residual -> hout ----------------
  {
    short8 a0[1], a1[1];
    loadA<1, 4>(T_, t, a0, a1);
#pragma unroll
    for (int nh = 0; nh < 2; ++nh) {
      f32x4 acc[1][2];
      acc[0][0] = (f32x4){0.f, 0.f, 0.f, 0.f};
      acc[0][1] = (f32x4){0.f, 0.f, 0.f, 0.f};
      mmh<1>(a0, a1, WT(15), acc, t, nh);
#pragma unroll
      for (int n2 = 0; n2 < 2; ++n2) {
        const int col = (nh * 2 + n2) * 16 + c15;
        const float nb = n_b2[col];
#pragma unroll
        for (int i = 0; i < 4; ++i) {
          const int row = q * 4 + i;
          if (row < 5) {
            const size_t ix = (size_t)(g * 5 + row) * HD + col;
            hout[ix] = gh[ix] + acc[0][n2][i] + nb;
          }
        }
      }
    }
  }
#undef WT
}

extern "C" void kernel_launch(void* const* d_in, const int* in_sizes, int n_in,
                              void* d_out, int out_size, void* d_ws, size_t ws_size,
                              hipStream_t stream) {
  if (n_in < 27) return;
  const float* gh    = (const float*)d_in[0];
  const float* coord = (const float*)d_in[1];
  const float* vel   = (const float*)d_in[2];
  const float* e_w1 = (const float*)d_in[4];
  const float* e_b1 = (const float*)d_in[5];
  const float* e_w2 = (const float*)d_in[6];
  const float* e_b2 = (const float*)d_in[7];
  const float* n_w1 = (const float*)d_in[8];
  const float* n_b1 = (const float*)d_in[9];
  const float* n_w2 = (const float*)d_in[10];
  const float* n_b2 = (const float*)d_in[11];
  const float* c_w1 = (const float*)d_in[12];
  const float* c_b1 = (const float*)d_in[13];
  const float* c_w2 = (const float*)d_in[14];
  const float* v_w1 = (const float*)d_in[15];
  const float* v_b1 = (const float*)d_in[16];
  const float* v_w2 = (const float*)d_in[17];
  const float* v_b2 = (const float*)d_in[18];
  const float* ic_wef = (const float*)d_in[19];
  const float* ic_pat = (const float*)d_in[20];
  const float* br_w1 = (const float*)d_in[21];
  const float* br_b1 = (const float*)d_in[22];
  const float* br_w2 = (const float*)d_in[23];
  const float* br_b2 = (const float*)d_in[24];
  const float* out_w = (const float*)d_in[25];
  const float* out_b = (const float*)d_in[26];

  const int N = in_sizes[0] / HD;  // 100000
  const int B = N / 5;             // 20000 graphs
  float* hout = (float*)d_out;
  float* cout = (float*)d_out + (size_t)N * HD;
  u16* W = (u16*)d_ws;  // 16*4096 + 2048 u16 = 135168 B

  prepack<<<17, 256, 0, stream>>>(br_w1, br_w2, out_w, e_w1, e_w2, c_w1, v_w1,
                                  n_w1, n_w2, ic_wef, W);

  const int blocks = (B + WPB - 1) / WPB;
  egcl_mfma<<<blocks, 64 * WPB, 0, stream>>>(
      gh, coord, vel, W, e_w1, e_b1, e_b2, n_b1, n_b2, c_b1, c_w2, v_b1, v_w2,
      v_b2, ic_pat, br_b1, br_b2, out_b, hout, cout, B);
}

// Round 8
// 322.769 us; speedup vs baseline: 1.8069x; 1.0227x over previous
//
#include <hip/hip_runtime.h>
#include <math.h>

#define HD 64
#define WPB 2

typedef unsigned short u16;
typedef unsigned int u32;
typedef __attribute__((ext_vector_type(8))) short short8;
typedef __attribute__((ext_vector_type(4))) float f32x4;

// 1-op bf16 convert (RNE). No builtin on gfx950; VOP3 so both srcs VGPR.
__device__ __forceinline__ u16 f2bf(float f) {
  u32 r;
  asm("v_cvt_pk_bf16_f32 %0, %1, %2" : "=v"(r) : "v"(f), "v"(f));
  return (u16)r;
}
__device__ __forceinline__ float bf2f(u16 x) {
  return __uint_as_float(((u32)x) << 16);
}
// 4-row-granule XOR swizzle: constant within an epilogue quad (i=0..3,
// r0%4==0) so stores fold to base + i*128B offsets; col-mode reads stay
// conflict-free; A-frag ds_read_b128 becomes ~4-way (1.58x, non-critical).
__device__ __forceinline__ int uswz(int row, int col) {
  return (row << 6) | (col ^ (((row >> 2) & 7) << 3));
}
__device__ __forceinline__ float rlane(float v, int l) {
  return __uint_as_float(__builtin_amdgcn_readlane(__float_as_uint(v), l));
}

// No explicit LDS fences: all LDS traffic is wave-private and compiler-visible
// (validated R4/R6/R7: absmax stable). Hoisted A-reads precede all same-buffer
// writes, so in-place phases are safe by program order.

// read A fragments once per phase (rows clamped to RMAX)
template <int MT, int RMAX>
__device__ __forceinline__ void loadA(const u16* A_, int t, short8* a0, short8* a1) {
  const int q8 = (t >> 4) << 3;
#pragma unroll
  for (int mt = 0; mt < MT; ++mt) {
    int row = mt * 16 + (t & 15);
    row = row > RMAX ? RMAX : row;
    const int idx = uswz(row, q8);
    a0[mt] = *reinterpret_cast<const short8*>(A_ + idx);
    a1[mt] = *reinterpret_cast<const short8*>(A_ + (idx ^ 32));
  }
}

// one N-half (cols nh*32..nh*32+31) of the 64x64 matmul
template <int MT>
__device__ __forceinline__ void mmh(const short8* a0, const short8* a1,
                                    const u16* __restrict__ WT, f32x4 (*acc)[2],
                                    int t, int nh) {
  const int c15 = t & 15;
  const int q8 = (t >> 4) << 3;
  short8 b[2][2];
#pragma unroll
  for (int n2 = 0; n2 < 2; ++n2) {
    const int nt = nh * 2 + n2;
#pragma unroll
    for (int s = 0; s < 2; ++s)
      b[n2][s] = *reinterpret_cast<const short8*>(WT + (nt * 16 + c15) * 64 + s * 32 + q8);
  }
#pragma unroll
  for (int mt = 0; mt < MT; ++mt) {
#pragma unroll
    for (int n2 = 0; n2 < 2; ++n2)
      acc[mt][n2] = __builtin_amdgcn_mfma_f32_16x16x32_bf16(a0[mt], b[n2][0], acc[mt][n2], 0, 0, 0);
#pragma unroll
    for (int n2 = 0; n2 < 2; ++n2)
      acc[mt][n2] = __builtin_amdgcn_mfma_f32_16x16x32_bf16(a1[mt], b[n2][1], acc[mt][n2], 0, 0, 0);
  }
}

// EPI: 1=store, 2=relu, 3=relu*M (MULT), 4=relu + D (RESID). Bias is folded
// into the accumulator init (C-in of the first MFMA), not added in epilogue.
template <int MT, int RMAX, int EPI>
__device__ __forceinline__ void run_phase(const u16* A_, u16* D_, const u16* M_,
                                          const u16* __restrict__ WT,
                                          const float* __restrict__ bias, int t,
                                          int rowoff = 0) {
  const int c15 = t & 15, q = t >> 4;
  constexpr int rowlim = (MT == 2) ? 25 : 5;
  short8 a0[MT], a1[MT];
  loadA<MT, RMAX>(A_, t, a0, a1);
#pragma unroll
  for (int nh = 0; nh < 2; ++nh) {
    f32x4 acc[MT][2];
#pragma unroll
    for (int n2 = 0; n2 < 2; ++n2) {
      const int col = (nh * 2 + n2) * 16 + c15;
      const float bb = bias ? bias[col] : 0.0f;
#pragma unroll
      for (int mt = 0; mt < MT; ++mt) acc[mt][n2] = (f32x4){bb, bb, bb, bb};
    }
    mmh<MT>(a0, a1, WT, acc, t, nh);
#pragma unroll
    for (int n2 = 0; n2 < 2; ++n2) {
      const int col = (nh * 2 + n2) * 16 + c15;
#pragma unroll
      for (int mt = 0; mt < MT; ++mt) {
        const int r0 = mt * 16 + q * 4;
        const int bix = uswz(r0 + rowoff, col);  // +i*64 per row (const swizzle)
#pragma unroll
        for (int i = 0; i < 4; ++i) {
          if (r0 + i < rowlim) {
            const int ix = bix + i * 64;
            float v = acc[mt][n2][i];
            if (EPI >= 2) v = fmaxf(v, 0.0f);
            if (EPI == 3) v *= bf2f(M_[ix]);
            if (EPI == 4) v += bf2f(D_[ix]);
            D_[ix] = f2bf(v);
          }
        }
      }
    }
  }
}

// ---- pre-pass: pack weights to bf16 transposed [n][k] ----
__global__ __launch_bounds__(256) void prepack(
    const float* __restrict__ br_w1, const float* __restrict__ br_w2,
    const float* __restrict__ out_w, const float* __restrict__ e_w1,
    const float* __restrict__ e_w2, const float* __restrict__ c_w1,
    const float* __restrict__ v_w1, const float* __restrict__ n_w1,
    const float* __restrict__ n_w2, const float* __restrict__ ic_wef,
    u16* __restrict__ W) {
  const int m = blockIdx.x;
  if (m == 16) {  // ic_wef^T, K padded 12->32 with zeros
    for (int e = threadIdx.x; e < 2048; e += blockDim.x) {
      const int n = e >> 5, k = e & 31;
      W[16 * 4096 + e] = (k < 12) ? f2bf(ic_wef[k * 64 + n]) : (u16)0;
    }
    return;
  }
  const float* src;
  switch (m) {
    case 0: src = br_w1; break;
    case 1: src = br_w1 + 4096; break;
    case 2: src = br_w1 + 8192; break;
    case 3: src = br_w2; break;
    case 4: src = br_w2 + 4096; break;
    case 5: src = br_w2 + 8192; break;
    case 6: src = out_w; break;
    case 7: src = e_w1; break;             // h[row]
    case 8: src = e_w1 + 64 * 64; break;   // h[col]
    case 9: src = e_w1 + 129 * 64; break;  // kemb
    case 10: src = e_w2; break;
    case 11: src = c_w1; break;
    case 12: src = v_w1; break;
    case 13: src = n_w1; break;            // h half
    case 14: src = n_w1 + 64 * 64; break;  // nagg half
    default: src = n_w2; break;
  }
  u16* dst = W + m * 4096;
  for (int e = threadIdx.x; e < 4096; e += blockDim.x) {
    const int n = e >> 6, k = e & 63;
    dst[e] = f2bf(src[k * 64 + n]);
  }
}

__global__ __launch_bounds__(64 * WPB, 4) void egcl_mfma(
    const float* __restrict__ gh, const float* __restrict__ gcoord,
    const float* __restrict__ gvel, const u16* __restrict__ Wg,
    const float* __restrict__ e_w1, const float* __restrict__ e_b1,
    const float* __restrict__ e_b2,
    const float* __restrict__ n_b1, const float* __restrict__ n_b2,
    const float* __restrict__ c_b1, const float* __restrict__ c_w2,
    const float* __restrict__ v_b1, const float* __restrict__ v_w2,
    const float* __restrict__ v_b2,
    const float* __restrict__ ic_pat,
    const float* __restrict__ br_b1, const float* __restrict__ br_b2,
    const float* __restrict__ out_b,
    float* __restrict__ hout, float* __restrict__ cout, int B) {
  // 5120 u16 per wave: H[5][64]@0, K@320, T@1920, U@3520 (each [25][64] swz)
  __shared__ __align__(16) u16 arena[WPB][5120];

  const int t = threadIdx.x & 63;
  const int wv = threadIdx.x >> 6;
  const int g = blockIdx.x * WPB + wv;
  if (g >= B) return;  // waves independent; no block barriers anywhere

  u16* AR = arena[wv];
  u16* H_ = AR;
  u16* K_ = AR + 320;
  u16* T_ = AR + 1920;
  u16* U_ = AR + 3520;
  u16* EFa = T_;  // EF lives in T before T's first matmul use: [25][32] plain
  const int c15 = t & 15, q = t >> 4, q8 = q << 3;
#define WT(m) (Wg + (m) * 4096)

  // ---------------- prologue: inputs ----------------
  float scvreg = 0.0f;
  if (t < 15) scvreg = gcoord[g * 15 + t];
  else if (t >= 16 && t < 31) scvreg = gvel[g * 15 + (t - 16)];

#pragma unroll
  for (int i = 0; i < 5; ++i) H_[uswz(i, t)] = f2bf(gh[(g * 5 + i) * HD + t]);

  // zero EF cols 12..31 (rows 0..24): 250 u32 slots
#pragma unroll
  for (int z = 0; z < 4; ++z) {
    const int e = t + z * 64;
    if (e < 250) {
      const int row = e / 10, cc = 12 + (e % 10) * 2;
      *reinterpret_cast<u32*>(EFa + row * 32 + cc) = 0u;
    }
  }

  float sqcc = 0.0f;  // squared coord-dist for this lane's tuple (radial)
  if (t < 25) {
    const int ti = t / 5, tj = t % 5;
    const float cix = __shfl(scvreg, ti * 3 + 0, 64), ciy = __shfl(scvreg, ti * 3 + 1, 64), ciz = __shfl(scvreg, ti * 3 + 2, 64);
    const float cjx = __shfl(scvreg, tj * 3 + 0, 64), cjy = __shfl(scvreg, tj * 3 + 1, 64), cjz = __shfl(scvreg, tj * 3 + 2, 64);
    const float vix = __shfl(scvreg, 16 + ti * 3 + 0, 64), viy = __shfl(scvreg, 16 + ti * 3 + 1, 64), viz = __shfl(scvreg, 16 + ti * 3 + 2, 64);
    const float vjx = __shfl(scvreg, 16 + tj * 3 + 0, 64), vjy = __shfl(scvreg, 16 + tj * 3 + 1, 64), vjz = __shfl(scvreg, 16 + tj * 3 + 2, 64);
    {
      const float dx = cix - cjx, dy = ciy - cjy, dz = ciz - cjz;
      sqcc = dx * dx + dy * dy + dz * dz;
    }
    auto sd = [](float sq) { return (sq > 0.0f) ? sqrtf(sq) : 0.0f; };
    float sq2;
    const float dcc = sd(sqcc);
    {
      const float dx = vix - vjx, dy = viy - vjy, dz = viz - vjz;
      sq2 = dx * dx + dy * dy + dz * dz;
    }
    const float dvv = sd(sq2);
    {
      const float dx = cix - vjx, dy = ciy - vjy, dz = ciz - vjz;
      sq2 = dx * dx + dy * dy + dz * dz;
    }
    const float dcv = sd(sq2);
    {
      const float dx = cjx - vix, dy = cjy - viy, dz = cjz - viz;
      sq2 = dx * dx + dy * dy + dz * dz;
    }
    const float dvc = sd(sq2);
    auto rbf3 = [&](float d, int base) {
      const float cut = (d <= 10.0f) ? (0.5f * (cosf(d * 0.31415926535897931f) + 1.0f)) : 0.0f;
      const float e = expf(-0.5f * d);
      const float u0 = e - 4.5399929762484854e-05f;
      const float u1 = e - 0.50002270f;
      const float u2 = e - 1.0f;
      const float BETA = 2.2502043f;
      EFa[t * 32 + base + 0] = f2bf((cut * expf(-BETA * u0 * u0) - 0.05f) * (1.0f / 0.15f));
      EFa[t * 32 + base + 1] = f2bf((cut * expf(-BETA * u1 * u1) - 0.05f) * (1.0f / 0.15f));
      EFa[t * 32 + base + 2] = f2bf((cut * expf(-BETA * u2 * u2) - 0.05f) * (1.0f / 0.15f));
    };
    rbf3(dcc, 0);
    rbf3(dvv, 3);
    rbf3(dcv, 6);
    rbf3(dvc, 9);
  }

  // ---------------- kemb = (ef @ ic_wef) * ic_pat[pattern] -> K ------------
  {
    short8 aE[2];
#pragma unroll
    for (int mt = 0; mt < 2; ++mt) {
      int row = mt * 16 + c15;
      row = row > 24 ? 24 : row;
      aE[mt] = *reinterpret_cast<const short8*>(EFa + row * 32 + q8);
    }
    const u16* WTp = Wg + 16 * 4096;
#pragma unroll
    for (int nh = 0; nh < 2; ++nh) {
      f32x4 acc[2][2];
#pragma unroll
      for (int mt = 0; mt < 2; ++mt)
#pragma unroll
        for (int n2 = 0; n2 < 2; ++n2) acc[mt][n2] = (f32x4){0.f, 0.f, 0.f, 0.f};
      short8 b[2];
#pragma unroll
      for (int n2 = 0; n2 < 2; ++n2)
        b[n2] = *reinterpret_cast<const short8*>(WTp + ((nh * 2 + n2) * 16 + c15) * 32 + q8);
#pragma unroll
      for (int mt = 0; mt < 2; ++mt)
#pragma unroll
        for (int n2 = 0; n2 < 2; ++n2)
          acc[mt][n2] = __builtin_amdgcn_mfma_f32_16x16x32_bf16(aE[mt], b[n2], acc[mt][n2], 0, 0, 0);
#pragma unroll
      for (int n2 = 0; n2 < 2; ++n2) {
        const int col = (nh * 2 + n2) * 16 + c15;
        const float p1 = ic_pat[64 + col], p2 = ic_pat[128 + col];
#pragma unroll
        for (int mt = 0; mt < 2; ++mt) {
          const int r0 = mt * 16 + q * 4;
          const int bix = uswz(r0, col);
#pragma unroll
          for (int i = 0; i < 4; ++i) {
            const int row = r0 + i;
            if (row < 25) {
              const bool diag = (row % 6) == 0;  // tuples 0,6,12,18,24
              K_[bix + i * 64] = f2bf(acc[mt][n2][i] * (diag ? p2 : p1));
            }
          }
        }
      }
    }
  }

  float svv[4];
  float svc[2][4];

  // ---------------- branch MLPs ----------------
  run_phase<2, 24, 2>(K_, T_, nullptr, WT(1), br_b1 + 64, t);    // k0 L1 -> T
  run_phase<2, 24, 2>(T_, U_, nullptr, WT(4), br_b2 + 64, t);    // k0 -> U
  run_phase<2, 24, 2>(K_, T_, nullptr, WT(2), br_b1 + 128, t);   // k1 L1 -> T
  run_phase<2, 24, 2>(T_, T_, nullptr, WT(5), br_b2 + 128, t);   // k1 -> T (in-place)

  // ---------------- einsum (col mode, j-outer) : mult -> U ----------------
  {
    float mu[25];
#pragma unroll
    for (int p = 0; p < 25; ++p) mu[p] = 0.0f;
#pragma unroll
    for (int j = 0; j < 5; ++j) {
      float k1r[5], k0c[5];
#pragma unroll
      for (int k = 0; k < 5; ++k) k1r[k] = bf2f(T_[uswz(j * 5 + k, t)]);
#pragma unroll
      for (int i = 0; i < 5; ++i) k0c[i] = bf2f(U_[uswz(i * 5 + j, t)]);
#pragma unroll
      for (int i = 0; i < 5; ++i)
#pragma unroll
        for (int k = 0; k < 5; ++k) mu[i * 5 + k] = fmaf(k0c[i], k1r[k], mu[i * 5 + k]);
    }
#pragma unroll
    for (int p = 0; p < 25; ++p) U_[uswz(p, t)] = f2bf(mu[p]);
  }

  run_phase<2, 24, 2>(K_, T_, nullptr, WT(0), br_b1, t);         // sm L1 -> T
  run_phase<2, 24, 3>(T_, T_, U_, WT(3), br_b2, t);              // z = relu(sm)*mult -> T
  run_phase<2, 24, 4>(T_, K_, nullptr, WT(6), out_b, t);         // residual -> K
  run_phase<2, 24, 1>(K_, T_, nullptr, WT(9), nullptr, t);       // accC -> T

  // ---------------- fused H-phase: accA -> U r0-4, accB -> U r8-12, VRED ---
  {
    short8 a0[1], a1[1];
    loadA<1, 4>(H_, t, a0, a1);
    float s[4] = {0.f, 0.f, 0.f, 0.f};
#pragma unroll
    for (int nh = 0; nh < 2; ++nh) {
      f32x4 aA[1][2], aB[1][2], aV[1][2];
#pragma unroll
      for (int n2 = 0; n2 < 2; ++n2) {
        aA[0][n2] = (f32x4){0.f, 0.f, 0.f, 0.f};
        aB[0][n2] = (f32x4){0.f, 0.f, 0.f, 0.f};
        const float bv = v_b1[(nh * 2 + n2) * 16 + c15];
        aV[0][n2] = (f32x4){bv, bv, bv, bv};
      }
      mmh<1>(a0, a1, WT(7), aA, t, nh);
      mmh<1>(a0, a1, WT(8), aB, t, nh);
      mmh<1>(a0, a1, WT(12), aV, t, nh);
#pragma unroll
      for (int n2 = 0; n2 < 2; ++n2) {
        const int col = (nh * 2 + n2) * 16 + c15;
        const int r0 = q * 4;
        const int bixA = uswz(r0, col);
        const int bixB = uswz(r0 + 8, col);
        const float w2v = v_w2[col];
#pragma unroll
        for (int i = 0; i < 4; ++i) {
          if (r0 + i < 5) {
            U_[bixA + i * 64] = f2bf(aA[0][n2][i]);
            U_[bixB + i * 64] = f2bf(aB[0][n2][i]);
          }
          s[i] += fmaxf(aV[0][n2][i], 0.0f) * w2v;
        }
      }
    }
#pragma unroll
    for (int i = 0; i < 4; ++i) {
      float ss = s[i];
      ss += __shfl_xor(ss, 1, 64);
      ss += __shfl_xor(ss, 2, 64);
      ss += __shfl_xor(ss, 4, 64);
      ss += __shfl_xor(ss, 8, 64);
      svv[i] = ss;
    }
  }

  // ---------------- edge assembly (col mode) ----------------
  {
    float aAc[5], aBc[5];
#pragma unroll
    for (int i = 0; i < 5; ++i) {
      aAc[i] = bf2f(U_[uswz(i, t)]);
      aBc[i] = bf2f(U_[uswz(8 + i, t)]);
    }
    const float eb1v = e_b1[t];
    const float wradv = e_w1[128 * HD + t];
    float ec[20];
#pragma unroll
    for (int p = 0; p < 20; ++p) {
      const int i = p >> 2, jj = p & 3;
      const int j = jj + (jj >= i ? 1 : 0);
      const float radial = rlane(sqcc, i * 5 + j);
      const float cc = bf2f(T_[uswz(i * 5 + j, t)]);
      ec[p] = fmaxf(aAc[i] + aBc[j] + radial * wradv + cc + eb1v, 0.0f);
    }
#pragma unroll
    for (int p = 0; p < 20; ++p) T_[uswz(p, t)] = f2bf(ec[p]);
  }

  run_phase<2, 24, 2>(T_, U_, nullptr, WT(10), e_b2, t);         // edge_feat -> U

  // ---------------- nagg -> K rows 0-4 ----------------
#pragma unroll
  for (int i = 0; i < 5; ++i) {
    float na = 0.0f;
#pragma unroll
    for (int jj = 0; jj < 4; ++jj) na += bf2f(U_[uswz(4 * i + jj, t)]);
    K_[uswz(i, t)] = f2bf(na);
  }

  // ---------------- c-model (CRED) ----------------
  {
    short8 a0[2], a1[2];
    loadA<2, 24>(U_, t, a0, a1);
    float s[2][4] = {{0.f, 0.f, 0.f, 0.f}, {0.f, 0.f, 0.f, 0.f}};
#pragma unroll
    for (int nh = 0; nh < 2; ++nh) {
      f32x4 acc[2][2];
#pragma unroll
      for (int n2 = 0; n2 < 2; ++n2) {
        const float bv = c_b1[(nh * 2 + n2) * 16 + c15];
#pragma unroll
        for (int mt = 0; mt < 2; ++mt) acc[mt][n2] = (f32x4){bv, bv, bv, bv};
      }
      mmh<2>(a0, a1, WT(11), acc, t, nh);
#pragma unroll
      for (int n2 = 0; n2 < 2; ++n2) {
        const int col = (nh * 2 + n2) * 16 + c15;
        const float w2v = c_w2[col];
#pragma unroll
        for (int mt = 0; mt < 2; ++mt)
#pragma unroll
          for (int i = 0; i < 4; ++i)
            s[mt][i] += fmaxf(acc[mt][n2][i], 0.0f) * w2v;
      }
    }
#pragma unroll
    for (int mt = 0; mt < 2; ++mt)
#pragma unroll
      for (int i = 0; i < 4; ++i) {
        float ss = s[mt][i];
        ss += __shfl_xor(ss, 1, 64);
        ss += __shfl_xor(ss, 2, 64);
        ss += __shfl_xor(ss, 4, 64);
        ss += __shfl_xor(ss, 8, 64);
        svc[mt][i] = ss;
      }
  }

  // ---------------- coord output (VALU only) ----------------
  {
    const float vb2 = v_b2[0];
    float coutreg = 0.0f;
#pragma unroll
    for (int i = 0; i < 5; ++i) {
      const float vmi = rlane(svv[i & 3], (i >> 2) << 4) + vb2;
#pragma unroll
      for (int dd = 0; dd < 3; ++dd) {
        const float ci = rlane(scvreg, i * 3 + dd);
        float s = 0.0f;
#pragma unroll
        for (int jj = 0; jj < 4; ++jj) {
          const int j = jj + (jj >= i ? 1 : 0);
          const int p = i * 4 + jj;
          const float cmp = rlane(svc[p >> 4][p & 3], ((p & 15) >> 2) << 4);
          float tr = (ci - rlane(scvreg, j * 3 + dd)) * cmp;
          tr = fminf(fmaxf(tr, -100.0f), 100.0f);
          s += tr;
        }
        const float val = ci + 0.25f * s + rlane(scvreg, 16 + i * 3 + dd) * vmi;
        if (t == i * 3 + dd) coutreg = val;
      }
    }
    if (t < 15) cout[g * 15 + t] = coutreg;
  }

  // ---------------- node model: L1 = relu(H@W13 + nagg@W14 + n_b1) -> T ----
  {
    short8 a0h[1], a1h[1], a0k[1], a1k[1];
    loadA<1, 4>(H_, t, a0h, a1h);
    loadA<1, 4>(K_, t, a0k, a1k);
#pragma unroll
    for (int nh = 0; nh < 2; ++nh) {
      f32x4 acc[1][2];
#pragma unroll
      for (int n2 = 0; n2 < 2; ++n2) {
        const float nb = n_b1[(nh * 2 + n2) * 16 + c15];
        acc[0][n2] = (f32x4){nb, nb, nb, nb};
      }
      mmh<1>(a0h, a1h, WT(13), acc, t, nh);
      mmh<1>(a0k, a1k, WT(14), acc, t, nh);
#pragma unroll
      for (int n2 = 0; n2 < 2; ++n2) {
        const int col = (nh * 2 + n2) * 16 + c15;
        const int r0 = q * 4;
        const int bix = uswz(r0, col);
#pragma unroll
        for (int i = 0; i < 4; ++i) {
          if (r0 + i < 5) T_[bix + i * 64] = f2bf(fmaxf(acc[0][n2][i], 0.0f));
        }
      }
    }
  }

  // ---------------- node model L2 + residual -> hout ----------------
  {
    short8 a0[1], a1[1];
    loadA<1, 4>(T_, t, a0, a1);
#pragma unroll
    for (int nh = 0; nh < 2; ++nh) {
      f32x4 acc[1][2];
#pragma unroll
      for (int n2 = 0; n2 < 2; ++n2) {
        const float nb = n_b2[(nh * 2 + n2) * 16 + c15];
        acc[0][n2] = (f32x4){nb, nb, nb, nb};
      }
      mmh<1>(a0, a1, WT(15), acc, t, nh);
#pragma unroll
      for (int n2 = 0; n2 < 2; ++n2) {
        const int col = (nh * 2 + n2) * 16 + c15;
#pragma unroll
        for (int i = 0; i < 4; ++i) {
          const int row = q * 4 + i;
          if (row < 5) {
            const size_t ix = (size_t)(g * 5 + row) * HD + col;
            hout[ix] = gh[ix] + acc[0][n2][i];
          }
        }
      }
    }
  }
#undef WT
}

extern "C" void kernel_launch(void* const* d_in, const int* in_sizes, int n_in,
                              void* d_out, int out_size, void* d_ws, size_t ws_size,
                              hipStream_t stream) {
  if (n_in < 27) return;
  const float* gh    = (const float*)d_in[0];
  const float* coord = (const float*)d_in[1];
  const float* vel   = (const float*)d_in[2];
  const float* e_w1 = (const float*)d_in[4];
  const float* e_b1 = (const float*)d_in[5];
  const float* e_w2 = (const float*)d_in[6];
  const float* e_b2 = (const float*)d_in[7];
  const float* n_w1 = (const float*)d_in[8];
  const float* n_b1 = (const float*)d_in[9];
  const float* n_w2 = (const float*)d_in[10];
  const float* n_b2 = (const float*)d_in[11];
  const float* c_w1 = (const float*)d_in[12];
  const float* c_b1 = (const float*)d_in[13];
  const float* c_w2 = (const float*)d_in[14];
  const float* v_w1 = (const float*)d_in[15];
  const float* v_b1 = (const float*)d_in[16];
  const float* v_w2 = (const float*)d_in[17];
  const float* v_b2 = (const float*)d_in[18];
  const float* ic_wef = (const float*)d_in[19];
  const float* ic_pat = (const float*)d_in[20];
  const float* br_w1 = (const float*)d_in[21];
  const float* br_b1 = (const float*)d_in[22];
  const float* br_w2 = (const float*)d_in[23];
  const float* br_b2 = (const float*)d_in[24];
  const float* out_w = (const float*)d_in[25];
  const float* out_b = (const float*)d_in[26];

  const int N = in_sizes[0] / HD;  // 100000
  const int B = N / 5;             // 20000 graphs
  float* hout = (float*)d_out;
  float* cout = (float*)d_out + (size_t)N * HD;
  u16* W = (u16*)d_ws;  // 16*4096 + 2048 u16 = 135168 B

  prepack<<<17, 256, 0, stream>>>(br_w1, br_w2, out_w, e_w1, e_w2, c_w1, v_w1,
                                  n_w1, n_w2, ic_wef, W);

  const int blocks = (B + WPB - 1) / WPB;
  egcl_mfma<<<blocks, 64 * WPB, 0, stream>>>(
      gh, coord, vel, W, e_w1, e_b1, e_b2, n_b1, n_b2, c_b1, c_w2, v_b1, v_w2,
      v_b2, ic_pat, br_b1, br_b2, out_b, hout, cout, B);
}